// Round 6
// baseline (220.439 us; speedup 1.0000x reference)
//
#include <hip/hip_runtime.h>

typedef unsigned short u16;
typedef unsigned int   u32;
typedef __bf16 v8bf __attribute__((ext_vector_type(8)));
typedef float  v4f  __attribute__((ext_vector_type(4)));
typedef u16    us4  __attribute__((ext_vector_type(4)));
typedef u32    ui4  __attribute__((ext_vector_type(4)));

__device__ __forceinline__ u16 f2bf(float f) {
  u32 u = __builtin_bit_cast(u32, f);
  u += 0x7fffu + ((u >> 16) & 1u);   // RNE
  return (u16)(u >> 16);
}
__device__ __forceinline__ float bf2f(u16 s) {
  u32 u = ((u32)s) << 16;
  return __builtin_bit_cast(float, u);
}

// 16B async global->LDS DMA; LDS dest = wave-uniform base + lane*16 (m97).
__device__ __forceinline__ void load_lds16(const u16* g, u16* l) {
  __builtin_amdgcn_global_load_lds(
      (const __attribute__((address_space(1))) u32*)g,
      (__attribute__((address_space(3))) u32*)l, 16, 0, 0);
}

// ---------------------------------------------------------------------------
// fp32 -> bf16 of x, Wl_in, Wg_in, Wf (flat) and Wl_out/Wg_out (TRANSPOSED).
// ---------------------------------------------------------------------------
__global__ void __launch_bounds__(256) cvt_all(
    const float* __restrict__ x,   const float* __restrict__ wli,
    const float* __restrict__ wlo, const float* __restrict__ wgi,
    const float* __restrict__ wgo, const float* __restrict__ wf,
    u16* __restrict__ out, u16* __restrict__ wloT, u16* __restrict__ wgoT)
{
  const int v = blockIdx.x * 256 + threadIdx.x;  // < 1703936
  const float* src; int obase; int mode = 0; u16* T = nullptr;
  if      (v < 1048576) { src = x;   obase = 0;       }
  else if (v < 1245184) { src = wli; obase = 1048576; }
  else if (v < 1310720) { src = wlo; obase = 1245184; mode = 1; T = wloT; }
  else if (v < 1507328) { src = wgi; obase = 1310720; }
  else if (v < 1572864) { src = wgo; obase = 1507328; mode = 1; T = wgoT; }
  else                  { src = wf;  obase = 1572864; }
  const int rel = v - obase;
  const float4 f = reinterpret_cast<const float4*>(src)[rel];
  us4 o;
  o.x = f2bf(f.x); o.y = f2bf(f.y); o.z = f2bf(f.z); o.w = f2bf(f.w);
  if (mode) {
    const int eb = rel * 4, c = eb >> 9, k = eb & 511;
#pragma unroll
    for (int i = 0; i < 4; ++i) T[(k + i) * 512 + c] = o[i];
  } else {
    int o4;
    if      (v < 1245184) o4 = v;            // xb | wli contiguous
    else if (v < 1507328) o4 = v - 65536;    // wgi
    else                  o4 = v - 131072;   // wfb
    reinterpret_cast<us4*>(out)[o4] = o;
  }
}

// ---------------------------------------------------------------------------
// bf16 NT GEMM body, 128x128 tile, BK=64, global_load_lds staging (m97) with
// SOURCE-XOR swizzle (conflict-free b128 fragment reads).
// ---------------------------------------------------------------------------
template<int RELU, int OUTF32, int TV, int BIASF>
__device__ __forceinline__ void gemm_body(
    u16* __restrict__ As, u16* __restrict__ Bs,
    const u16* __restrict__ A, const int lda,
    const u16* __restrict__ B, const int ldb,
    const float* __restrict__ bias, void* __restrict__ C,
    u16* __restrict__ vt, const int bm, const int bn,
    const int K, const int ldc, const int colofs)
{
  const int tid  = threadIdx.x;
  const int lane = tid & 63;
  const int w    = tid >> 6;
  const int lid  = lane & 15;
  const int quad = lane >> 4;
  const int wr = w >> 1, wc = w & 1;

  v4f acc[4][4];
#pragma unroll
  for (int i = 0; i < 4; ++i)
#pragma unroll
    for (int j = 0; j < 4; ++j)
      acc[i][j] = (v4f){0.f, 0.f, 0.f, 0.f};

  const int dr = lane >> 3;              // row within 8-row DMA group
  const int cs = ((lane ^ dr) & 7) * 8;  // source chunk = dc ^ dr (swizzle)

  for (int k0 = 0; k0 < K; k0 += 64) {
#pragma unroll
    for (int p = 0; p < 4; ++p) {
      const int g   = w + p * 4;
      const int row = g * 8 + dr;
      load_lds16(A + (size_t)(bm + row) * lda + k0 + cs, As + g * 512);
      load_lds16(B + (size_t)(bn + row) * ldb + k0 + cs, Bs + g * 512);
    }
    __syncthreads();
#pragma unroll
    for (int kk = 0; kk < 2; ++kk) {
      v8bf af[4], bfr[4];
#pragma unroll
      for (int mi = 0; mi < 4; ++mi)
        af[mi] = *reinterpret_cast<const v8bf*>(
            &As[(wr * 64 + mi * 16 + lid) * 64 + (((kk * 4 + quad) ^ (lid & 7)) * 8)]);
#pragma unroll
      for (int ni = 0; ni < 4; ++ni)
        bfr[ni] = *reinterpret_cast<const v8bf*>(
            &Bs[(wc * 64 + ni * 16 + lid) * 64 + (((kk * 4 + quad) ^ (lid & 7)) * 8)]);
#pragma unroll
      for (int mi = 0; mi < 4; ++mi)
#pragma unroll
        for (int ni = 0; ni < 4; ++ni)
          acc[mi][ni] = __builtin_amdgcn_mfma_f32_16x16x32_bf16(
              af[mi], bfr[ni], acc[mi][ni], 0, 0, 0);
    }
    __syncthreads();
  }

  float bv[4];
#pragma unroll
  for (int ni = 0; ni < 4; ++ni)
    bv[ni] = BIASF ? bias[bn + wc * 64 + ni * 16 + lid] : 0.f;

  if (TV && bn >= 1024) {
#pragma unroll
    for (int mi = 0; mi < 4; ++mi) {
      const int m0 = bm + wr * 64 + mi * 16 + quad * 4;
#pragma unroll
      for (int ni = 0; ni < 4; ++ni) {
        const int n = bn + wc * 64 + ni * 16 + lid - 1024;  // 0..511 = (h,d)
        us4 pk;
#pragma unroll
        for (int r = 0; r < 4; ++r) pk[r] = f2bf(acc[mi][ni][r] + bv[ni]);
        const size_t idx =
            ((size_t)((m0 >> 10) * 8 + (n >> 6)) * 64 + (n & 63)) * 1024 + (m0 & 1023);
        *reinterpret_cast<us4*>(&vt[idx]) = pk;
      }
    }
  } else {
#pragma unroll
    for (int mi = 0; mi < 4; ++mi) {
#pragma unroll
      for (int ni = 0; ni < 4; ++ni) {
        const int n = bn + wc * 64 + ni * 16 + lid;
#pragma unroll
        for (int r = 0; r < 4; ++r) {
          const int m = bm + wr * 64 + mi * 16 + quad * 4 + r;
          float v = acc[mi][ni][r] + bv[ni];
          if (RELU) v = fmaxf(v, 0.f);
          if (OUTF32)
            reinterpret_cast<float*>(C)[(size_t)m * ldc + colofs + n] = v;
          else
            reinterpret_cast<u16*>(C)[(size_t)m * ldc + colofs + n] = f2bf(v);
        }
      }
    }
  }
}

// Both QKV projections, one launch. bx<12: local set; else global set (+TV).
__global__ void __launch_bounds__(256) qkv_dual(
    const u16* __restrict__ xb,
    const u16* __restrict__ wli, const float* __restrict__ bli, u16* __restrict__ qkv_l,
    const u16* __restrict__ wgi, const float* __restrict__ bgi, u16* __restrict__ qkv_g,
    u16* __restrict__ vt)
{
  __shared__ __align__(16) u16 As[128 * 64];
  __shared__ __align__(16) u16 Bs[128 * 64];
  if (blockIdx.x < 12)
    gemm_body<0,0,0,1>(As, Bs, xb, 512, wli, 512, bli, qkv_l, nullptr,
                       blockIdx.y * 128, blockIdx.x * 128, 512, 1536, 0);
  else
    gemm_body<0,0,1,1>(As, Bs, xb, 512, wgi, 512, bgi, qkv_g, vt,
                       blockIdx.y * 128, (blockIdx.x - 12) * 128, 512, 1536, 0);
}

// ---------------------------------------------------------------------------
// MEGA, interleaved dispatch for co-residency (m114: MFMA-wave + VALU-wave on
// one CU overlap fully):
//   bx <  32              : weight-combine GEMMs (Wc = Wf_half @ WxT)
//   bx <  40              : combined-bias reduction
//   bx >= 40, group even  : flash-attention   (idx = (g>>1)*8 + sub)
//   bx >= 40, group odd   : local banded attn (same idx decomposition)
// Stride-8 alternation keeps each XCD fed with both types; flash retains its
// head->XCD pinning (sub = bx&7; 40 % 8 == 0 so XCD = sub).
// Flash P stores are TRUNCATED bf16 (bits>>16 -> ds_write_b16_d16_hi, ~free)
// instead of 4-VALU RNE; l is the MFMA-sum of the SAME truncated P, so the
// O/l normalization stays self-consistent.
// ---------------------------------------------------------------------------
__global__ void __launch_bounds__(256, 4) mega(
    const u16* __restrict__ qkv, const u16* __restrict__ vt, u16* __restrict__ outp,
    const u16* __restrict__ wfb, const u16* __restrict__ wloT, const u16* __restrict__ wgoT,
    u16* __restrict__ Wc, const float* __restrict__ blo, const float* __restrict__ bgo,
    const float* __restrict__ bff, float* __restrict__ bias_c,
    const u16* __restrict__ qkvl, u16* __restrict__ attn_l)
{
  __shared__ __align__(16) u16 smem[20480];  // 40 KB
  const int bx   = blockIdx.x;
  const int tid  = threadIdx.x;
  const int lane = tid & 63;
  const int w    = tid >> 6;

  if (bx < 32) {                  // ---- Wc[e][half*512+k] = Wf_half @ WxT ----
    const int half = bx >> 4, rem = bx & 15;
    gemm_body<0,0,0,0>(smem, smem + 8192, wfb + half * 512, 1024,
                       (half ? wgoT : wloT), 512, nullptr, Wc, nullptr,
                       (rem >> 2) * 128, (rem & 3) * 128, 512, 1024, half * 512);
    return;
  }
  if (bx < 40) {                  // ---- bias_c[e] = bf[e] + Wf[e,:].bcat ----
    const int e = (bx - 32) * 64 + w * 16;
    for (int t = 0; t < 16; ++t) {
      float sum = 0.f;
#pragma unroll
      for (int j = 0; j < 16; ++j) {
        const int c2 = j * 64 + lane;
        const float b = (c2 < 512) ? blo[c2] : bgo[c2 - 512];
        sum += bf2f(wfb[(size_t)(e + t) * 1024 + c2]) * b;
      }
#pragma unroll
      for (int msk = 32; msk >= 1; msk >>= 1) sum += __shfl_xor(sum, msk);
      if (lane == 0) bias_c[e + t] = bff[e + t] + sum;
    }
    return;
  }

  const int u   = bx - 40;        // 0..2047
  const int g   = u >> 3;
  const int sub = u & 7;
  const int idx = (g >> 1) * 8 + sub;   // 0..1023 per type

  if (g & 1) {                    // ---- local banded attention (|i-j|<=3) ----
    const int lgroup = idx >> 3;
    const int qt = lgroup & 15;
    const int bh = ((idx & 7) << 3) | (lgroup >> 4);
    const int b = bh >> 3, h = bh & 7;
    const int i0 = qt * 64;
    const size_t base = (size_t)b * 1024 * 1536;
    u16* Kl = smem;                // 70*64
    u16* Vl = smem + 4480;

    for (int i2 = tid; i2 < 1120; i2 += 256) {
      const int isV  = i2 >= 560;
      const int i3 = isV ? i2 - 560 : i2;
      const int row = i3 >> 3, ch = i3 & 7;
      const int jc = min(max(i0 - 3 + row, 0), 1023);
      const ui4 d = *reinterpret_cast<const ui4*>(
          qkvl + base + (size_t)jc * 1536 + (isV ? 1024 : 512) + h * 64 + ch * 8);
      *reinterpret_cast<ui4*>(&(isV ? Vl : Kl)[row * 64 + ch * 8]) = d;
    }
    __syncthreads();

    for (int t = 0; t < 16; ++t) {
      const int i = i0 + w * 16 + t;
      const float qd = bf2f(qkvl[base + (size_t)i * 1536 + h * 64 + lane]);
      float denom = 0.f, accv = 0.f;
#pragma unroll
      for (int tt = 0; tt < 7; ++tt) {
        const int j = i - 3 + tt;
        const bool ok = (j >= 0) && (j <= 1023);
        const int ridx = w * 16 + t + tt;
        float pr = qd * bf2f(Kl[ridx * 64 + lane]);
#pragma unroll
        for (int msk = 32; msk >= 1; msk >>= 1) pr += __shfl_xor(pr, msk);
        const float p = ok ? __expf(pr * 0.125f) : 0.f;
        denom += p;
        accv += p * bf2f(Vl[ridx * 64 + lane]);
      }
      attn_l[(size_t)(b * 1024 + i) * 1536 + h * 64 + lane] = f2bf(accv / denom);
    }
    return;
  }

  // ---- flash attention (DMA-staged dbuf, source-XOR swizzle, fixed-base) ----
  const int lid  = lane & 15;
  const int quad = lane >> 4;
  const int fgroup = idx >> 3;
  const int qt = fgroup & 15;
  const int bh = ((idx & 7) << 3) | (fgroup >> 4);   // head pinned to XCD=sub
  const int b = bh >> 3, h = bh & 7;
  const size_t base = (size_t)b * 1024 * 1536;

  v8bf aq[2];
  {
    const size_t qoff = base + (size_t)(qt * 64 + w * 16 + lid) * 1536 + h * 64 + quad * 8;
    aq[0] = *reinterpret_cast<const v8bf*>(qkv + qoff);
    aq[1] = *reinterpret_cast<const v8bf*>(qkv + qoff + 32);
#pragma unroll
    for (int k = 0; k < 2; ++k)
#pragma unroll
      for (int i = 0; i < 8; ++i)
        aq[k][i] = (__bf16)((float)aq[k][i] * 0.125f);  // exact
  }
  v8bf ones;
#pragma unroll
  for (int i = 0; i < 8; ++i) ones[i] = (__bf16)1.0f;

  v4f o[4], lacc = (v4f){0.f, 0.f, 0.f, 0.f};
#pragma unroll
  for (int nd = 0; nd < 4; ++nd) o[nd] = (v4f){0.f, 0.f, 0.f, 0.f};

  u16* Ps = smem + 16384;
  const int dr = lane >> 3;
  const int dc = lane & 7;
#define STAGE(KT, BI)                                                          \
  {                                                                            \
    _Pragma("unroll") for (int p = 0; p < 2; ++p) {                            \
      const int r = (w + p * 4) * 8 + dr;                                      \
      const int cs = (dc ^ (r & 7)) * 8;                                       \
      load_lds16(qkv + base + (size_t)((KT) * 64 + r) * 1536 + 512 + h * 64 + cs, \
                 smem + (BI) * 4096 + (w + p * 4) * 512);                      \
      load_lds16(vt + ((size_t)bh * 64 + r) * 1024 + (KT) * 64 + cs,           \
                 smem + 8192 + (BI) * 4096 + (w + p * 4) * 512);               \
    }                                                                          \
  }
  STAGE(0, 0);

  for (int kt = 0; kt < 16; ++kt) {
    __syncthreads();
    if (kt < 15) STAGE(kt + 1, (kt + 1) & 1);
    const u16* Ks = smem + (kt & 1) * 4096;
    const u16* Vs = smem + 8192 + (kt & 1) * 4096;

    v4f s[4];
#pragma unroll
    for (int nk = 0; nk < 4; ++nk) s[nk] = (v4f){0.f, 0.f, 0.f, 0.f};
#pragma unroll
    for (int kk = 0; kk < 2; ++kk)
#pragma unroll
      for (int nk = 0; nk < 4; ++nk) {
        const v8bf bk = *reinterpret_cast<const v8bf*>(
            &Ks[(nk * 16 + lid) * 64 + (((kk * 4 + quad) ^ (lid & 7)) * 8)]);
        s[nk] = __builtin_amdgcn_mfma_f32_16x16x32_bf16(aq[kk], bk, s[nk], 0, 0, 0);
      }

#pragma unroll
    for (int nk = 0; nk < 4; ++nk) {
#pragma unroll
      for (int r = 0; r < 4; ++r) {
        const float p = __expf(s[nk][r]);
        const int prow = quad * 4 + r;
        const int pcol = nk * 16 + lid;
        // truncated bf16 (ds_write_b16_d16_hi) — l sums the same truncation
        Ps[w * 1024 + prow * 64 + (((pcol >> 3) ^ (prow & 7)) * 8) + (pcol & 7)] =
            (u16)(__builtin_bit_cast(u32, p) >> 16);
      }
    }

    // O^T = V^T P^T
#pragma unroll
    for (int kk = 0; kk < 2; ++kk) {
      const v8bf ap = *reinterpret_cast<const v8bf*>(
          &Ps[w * 1024 + lid * 64 + (((kk * 4 + quad) ^ (lid & 7)) * 8)]);
      lacc = __builtin_amdgcn_mfma_f32_16x16x32_bf16(ones, ap, lacc, 0, 0, 0);
#pragma unroll
      for (int nd = 0; nd < 4; ++nd) {
        const v8bf av = *reinterpret_cast<const v8bf*>(
            &Vs[(nd * 16 + lid) * 64 + (((kk * 4 + quad) ^ (lid & 7)) * 8)]);
        o[nd] = __builtin_amdgcn_mfma_f32_16x16x32_bf16(av, ap, o[nd], 0, 0, 0);
      }
    }
  }
#undef STAGE

  const float inv = 1.f / lacc[0];
  const int tok = b * 1024 + qt * 64 + w * 16 + lid;
#pragma unroll
  for (int nd = 0; nd < 4; ++nd) {
    us4 pk;
#pragma unroll
    for (int r = 0; r < 4; ++r) pk[r] = f2bf(o[nd][r] * inv);
    *reinterpret_cast<us4*>(&outp[(size_t)tok * 512 + h * 64 + nd * 16 + quad * 4]) = pk;
  }
}

// ---------------------------------------------------------------------------
// Final fused GEMM: out = ReLU([attn_l|attn_g] @ Wc^T + bias_c), fp32 out.
// attn_l lives in qkv_g's V-slots (lda 1536); attn_g is dense (lda 512).
// ---------------------------------------------------------------------------
__global__ void __launch_bounds__(256) gemm_final(
    const u16* __restrict__ Al, const u16* __restrict__ Ag,
    const u16* __restrict__ Bw, const float* __restrict__ biasc,
    float* __restrict__ out)
{
  __shared__ __align__(16) u16 As[64 * 64];
  __shared__ __align__(16) u16 Bs[128 * 64];
  const int tid  = threadIdx.x;
  const int lane = tid & 63;
  const int w    = tid >> 6;
  const int lid  = lane & 15;
  const int quad = lane >> 4;
  const int bm = blockIdx.y * 64;
  const int bn = blockIdx.x * 128;

  v4f acc[4][2];
#pragma unroll
  for (int i = 0; i < 4; ++i)
#pragma unroll
    for (int j = 0; j < 2; ++j)
      acc[i][j] = (v4f){0.f, 0.f, 0.f, 0.f};

  const int dr = lane >> 3;
  const int cs = ((lane ^ dr) & 7) * 8;

  for (int k0 = 0; k0 < 1024; k0 += 64) {
    const int half = k0 >> 9;
    const u16* Asrc = half ? Ag : Al;
    const int  lda  = half ? 512 : 1536;
    const int  kcol = k0 & 511;
#pragma unroll
    for (int p = 0; p < 2; ++p) {
      const int g   = w + p * 4;
      const int row = g * 8 + dr;
      load_lds16(Asrc + (size_t)(bm + row) * lda + kcol + cs, As + g * 512);
    }
#pragma unroll
    for (int p = 0; p < 4; ++p) {
      const int g   = w + p * 4;
      const int row = g * 8 + dr;
      load_lds16(Bw + (size_t)(bn + row) * 1024 + k0 + cs, Bs + g * 512);
    }
    __syncthreads();
#pragma unroll
    for (int kk = 0; kk < 2; ++kk) {
      v8bf af[4], bfr[2];
#pragma unroll
      for (int mi = 0; mi < 4; ++mi)
        af[mi] = *reinterpret_cast<const v8bf*>(
            &As[(mi * 16 + lid) * 64 + (((kk * 4 + quad) ^ (lid & 7)) * 8)]);
#pragma unroll
      for (int ni = 0; ni < 2; ++ni)
        bfr[ni] = *reinterpret_cast<const v8bf*>(
            &Bs[(w * 32 + ni * 16 + lid) * 64 + (((kk * 4 + quad) ^ (lid & 7)) * 8)]);
#pragma unroll
      for (int mi = 0; mi < 4; ++mi)
#pragma unroll
        for (int ni = 0; ni < 2; ++ni)
          acc[mi][ni] = __builtin_amdgcn_mfma_f32_16x16x32_bf16(
              af[mi], bfr[ni], acc[mi][ni], 0, 0, 0);
    }
    __syncthreads();
  }

#pragma unroll
  for (int mi = 0; mi < 4; ++mi) {
#pragma unroll
    for (int ni = 0; ni < 2; ++ni) {
      const int n = bn + w * 32 + ni * 16 + lid;
      const float bv = biasc[n];
#pragma unroll
      for (int r = 0; r < 4; ++r) {
        const int m = bm + mi * 16 + quad * 4 + r;
        out[(size_t)m * 512 + n] = fmaxf(acc[mi][ni][r] + bv, 0.f);
      }
    }
  }
}

// ---------------------------------------------------------------------------
// Workspace (u16 elems), total 36701184 = 73.4 MB:
//   0        xb (dead after qkv_dual -> attn_g) | 4194304 wli | 4980736 wgi
//   5767168  wfb | 6291456 qkv_l | 18874368 qkv_g (V-thirds = attn_l)
//   31457280 vt | 35651584 Wc | 36175872 bias_c | 36176896 wloT | 36439040 wgoT
// ---------------------------------------------------------------------------
extern "C" void kernel_launch(void* const* d_in, const int* in_sizes, int n_in,
                              void* d_out, int out_size, void* d_ws, size_t ws_size,
                              hipStream_t stream) {
  (void)in_sizes; (void)n_in; (void)out_size; (void)ws_size;
  const float* x   = (const float*)d_in[0];
  const float* Wli = (const float*)d_in[1];
  const float* bli = (const float*)d_in[2];
  const float* Wlo = (const float*)d_in[3];
  const float* blo = (const float*)d_in[4];
  const float* Wgi = (const float*)d_in[5];
  const float* bgi = (const float*)d_in[6];
  const float* Wgo = (const float*)d_in[7];
  const float* bgo = (const float*)d_in[8];
  const float* Wf  = (const float*)d_in[9];
  const float* bff = (const float*)d_in[10];
  float* out = (float*)d_out;

  u16* W      = (u16*)d_ws;
  u16* xb     = W + 0;
  u16* wli    = W + 4194304;
  u16* wgi    = W + 4980736;
  u16* wfb    = W + 5767168;
  u16* qkv_l  = W + 6291456;
  u16* qkv_g  = W + 18874368;
  u16* vt     = W + 31457280;
  u16* Wc     = W + 35651584;
  float* bias_c = (float*)(W + 36175872);
  u16* wloT   = W + 36176896;
  u16* wgoT   = W + 36439040;
  u16* attn_g = W + 0;                  // over dead xb
  u16* attn_l = qkv_g + 1024;           // dead V-thirds of qkv_g, lda 1536

  cvt_all<<<6656, 256, 0, stream>>>(x, Wli, Wlo, Wgi, Wgo, Wf, W, wloT, wgoT);
  qkv_dual<<<dim3(24, 64), 256, 0, stream>>>(xb, wli, bli, qkv_l, wgi, bgi, qkv_g, vt);
  mega<<<2088, 256, 0, stream>>>(qkv_g, vt, attn_g, wfb, wloT, wgoT, Wc,
                                 blo, bgo, bff, bias_c, qkv_l, attn_l);
  gemm_final<<<dim3(4, 128), 256, 0, stream>>>(attn_l, attn_g, Wc, bias_c, out);
}

// Round 7
// 182.606 us; speedup vs baseline: 1.2072x; 1.2072x over previous
//
#include <hip/hip_runtime.h>

typedef unsigned short u16;
typedef unsigned int   u32;
typedef __bf16 v8bf __attribute__((ext_vector_type(8)));
typedef float  v4f  __attribute__((ext_vector_type(4)));
typedef u16    us4  __attribute__((ext_vector_type(4)));
typedef u32    ui4  __attribute__((ext_vector_type(4)));

__device__ __forceinline__ u16 f2bf(float f) {
  u32 u = __builtin_bit_cast(u32, f);
  u += 0x7fffu + ((u >> 16) & 1u);   // RNE
  return (u16)(u >> 16);
}
__device__ __forceinline__ float bf2f(u16 s) {
  u32 u = ((u32)s) << 16;
  return __builtin_bit_cast(float, u);
}

// 16B async global->LDS DMA; LDS dest = wave-uniform base + lane*16 (m97).
__device__ __forceinline__ void load_lds16(const u16* g, u16* l) {
  __builtin_amdgcn_global_load_lds(
      (const __attribute__((address_space(1))) u32*)g,
      (__attribute__((address_space(3))) u32*)l, 16, 0, 0);
}

// ---------------------------------------------------------------------------
// fp32 -> bf16 of x, Wl_in, Wg_in, Wf (flat) and Wl_out/Wg_out (TRANSPOSED).
// ---------------------------------------------------------------------------
__global__ void __launch_bounds__(256) cvt_all(
    const float* __restrict__ x,   const float* __restrict__ wli,
    const float* __restrict__ wlo, const float* __restrict__ wgi,
    const float* __restrict__ wgo, const float* __restrict__ wf,
    u16* __restrict__ out, u16* __restrict__ wloT, u16* __restrict__ wgoT)
{
  const int v = blockIdx.x * 256 + threadIdx.x;  // < 1703936
  const float* src; int obase; int mode = 0; u16* T = nullptr;
  if      (v < 1048576) { src = x;   obase = 0;       }
  else if (v < 1245184) { src = wli; obase = 1048576; }
  else if (v < 1310720) { src = wlo; obase = 1245184; mode = 1; T = wloT; }
  else if (v < 1507328) { src = wgi; obase = 1310720; }
  else if (v < 1572864) { src = wgo; obase = 1507328; mode = 1; T = wgoT; }
  else                  { src = wf;  obase = 1572864; }
  const int rel = v - obase;
  const float4 f = reinterpret_cast<const float4*>(src)[rel];
  us4 o;
  o.x = f2bf(f.x); o.y = f2bf(f.y); o.z = f2bf(f.z); o.w = f2bf(f.w);
  if (mode) {
    const int eb = rel * 4, c = eb >> 9, k = eb & 511;
#pragma unroll
    for (int i = 0; i < 4; ++i) T[(k + i) * 512 + c] = o[i];
  } else {
    int o4;
    if      (v < 1245184) o4 = v;            // xb | wli contiguous
    else if (v < 1507328) o4 = v - 65536;    // wgi
    else                  o4 = v - 131072;   // wfb
    reinterpret_cast<us4*>(out)[o4] = o;
  }
}

// ---------------------------------------------------------------------------
// bf16 NT GEMM body, 128x128 tile, BK=64, global_load_lds staging (m97) with
// SOURCE-XOR swizzle (conflict-free b128 fragment reads).
// ---------------------------------------------------------------------------
template<int RELU, int OUTF32, int TV, int BIASF>
__device__ __forceinline__ void gemm_body(
    u16* __restrict__ As, u16* __restrict__ Bs,
    const u16* __restrict__ A, const int lda,
    const u16* __restrict__ B, const int ldb,
    const float* __restrict__ bias, void* __restrict__ C,
    u16* __restrict__ vt, const int bm, const int bn,
    const int K, const int ldc, const int colofs)
{
  const int tid  = threadIdx.x;
  const int lane = tid & 63;
  const int w    = tid >> 6;
  const int lid  = lane & 15;
  const int quad = lane >> 4;
  const int wr = w >> 1, wc = w & 1;

  v4f acc[4][4];
#pragma unroll
  for (int i = 0; i < 4; ++i)
#pragma unroll
    for (int j = 0; j < 4; ++j)
      acc[i][j] = (v4f){0.f, 0.f, 0.f, 0.f};

  const int dr = lane >> 3;              // row within 8-row DMA group
  const int cs = ((lane ^ dr) & 7) * 8;  // source chunk = dc ^ dr (swizzle)

  for (int k0 = 0; k0 < K; k0 += 64) {
#pragma unroll
    for (int p = 0; p < 4; ++p) {
      const int g   = w + p * 4;
      const int row = g * 8 + dr;
      load_lds16(A + (size_t)(bm + row) * lda + k0 + cs, As + g * 512);
      load_lds16(B + (size_t)(bn + row) * ldb + k0 + cs, Bs + g * 512);
    }
    __syncthreads();
#pragma unroll
    for (int kk = 0; kk < 2; ++kk) {
      v8bf af[4], bfr[4];
#pragma unroll
      for (int mi = 0; mi < 4; ++mi)
        af[mi] = *reinterpret_cast<const v8bf*>(
            &As[(wr * 64 + mi * 16 + lid) * 64 + (((kk * 4 + quad) ^ (lid & 7)) * 8)]);
#pragma unroll
      for (int ni = 0; ni < 4; ++ni)
        bfr[ni] = *reinterpret_cast<const v8bf*>(
            &Bs[(wc * 64 + ni * 16 + lid) * 64 + (((kk * 4 + quad) ^ (lid & 7)) * 8)]);
#pragma unroll
      for (int mi = 0; mi < 4; ++mi)
#pragma unroll
        for (int ni = 0; ni < 4; ++ni)
          acc[mi][ni] = __builtin_amdgcn_mfma_f32_16x16x32_bf16(
              af[mi], bfr[ni], acc[mi][ni], 0, 0, 0);
    }
    __syncthreads();
  }

  float bv[4];
#pragma unroll
  for (int ni = 0; ni < 4; ++ni)
    bv[ni] = BIASF ? bias[bn + wc * 64 + ni * 16 + lid] : 0.f;

  if (TV && bn >= 1024) {
#pragma unroll
    for (int mi = 0; mi < 4; ++mi) {
      const int m0 = bm + wr * 64 + mi * 16 + quad * 4;
#pragma unroll
      for (int ni = 0; ni < 4; ++ni) {
        const int n = bn + wc * 64 + ni * 16 + lid - 1024;  // 0..511 = (h,d)
        us4 pk;
#pragma unroll
        for (int r = 0; r < 4; ++r) pk[r] = f2bf(acc[mi][ni][r] + bv[ni]);
        const size_t idx =
            ((size_t)((m0 >> 10) * 8 + (n >> 6)) * 64 + (n & 63)) * 1024 + (m0 & 1023);
        *reinterpret_cast<us4*>(&vt[idx]) = pk;
      }
    }
  } else {
#pragma unroll
    for (int mi = 0; mi < 4; ++mi) {
#pragma unroll
      for (int ni = 0; ni < 4; ++ni) {
        const int n = bn + wc * 64 + ni * 16 + lid;
#pragma unroll
        for (int r = 0; r < 4; ++r) {
          const int m = bm + wr * 64 + mi * 16 + quad * 4 + r;
          float v = acc[mi][ni][r] + bv[ni];
          if (RELU) v = fmaxf(v, 0.f);
          if (OUTF32)
            reinterpret_cast<float*>(C)[(size_t)m * ldc + colofs + n] = v;
          else
            reinterpret_cast<u16*>(C)[(size_t)m * ldc + colofs + n] = f2bf(v);
        }
      }
    }
  }
}

// Both QKV projections, one launch. bx<12: local set; else global set (+TV).
__global__ void __launch_bounds__(256) qkv_dual(
    const u16* __restrict__ xb,
    const u16* __restrict__ wli, const float* __restrict__ bli, u16* __restrict__ qkv_l,
    const u16* __restrict__ wgi, const float* __restrict__ bgi, u16* __restrict__ qkv_g,
    u16* __restrict__ vt)
{
  __shared__ __align__(16) u16 As[128 * 64];
  __shared__ __align__(16) u16 Bs[128 * 64];
  if (blockIdx.x < 12)
    gemm_body<0,0,0,1>(As, Bs, xb, 512, wli, 512, bli, qkv_l, nullptr,
                       blockIdx.y * 128, blockIdx.x * 128, 512, 1536, 0);
  else
    gemm_body<0,0,1,1>(As, Bs, xb, 512, wgi, 512, bgi, qkv_g, vt,
                       blockIdx.y * 128, (blockIdx.x - 12) * 128, 512, 1536, 0);
}

// ---------------------------------------------------------------------------
// MEGA (round-5 tail ordering — interleave regressed, r6 post-mortem: flash
// and local BOTH bottleneck the shared LDS pipe, so co-residency sums):
//   bx < 1024 : flash-attention (XCD-pinned heads)
//   1024..1055: weight-combine GEMMs; 1056..1063: combined-bias reduction
//   1064..2087: local banded attention, RE-PARALLELIZED:
//     lane = (query q=lane>>2, oct=lane&3); each lane owns 16 dh elements.
//     All 16 queries/wave advance per key-offset: 4 ds_read_b128 + 2 shfl +
//     ~70 VALU per tt -> ~50 DS instrs/wave vs ~900 in the old per-query loop.
//     K/V staged at stride 72 (144 B rows): lane bank-starts tile all 32
//     banks uniformly -> conflict-free at the b128 throughput floor.
// ---------------------------------------------------------------------------
__global__ void __launch_bounds__(256, 4) mega(
    const u16* __restrict__ qkv, const u16* __restrict__ vt, u16* __restrict__ outp,
    const u16* __restrict__ wfb, const u16* __restrict__ wloT, const u16* __restrict__ wgoT,
    u16* __restrict__ Wc, const float* __restrict__ blo, const float* __restrict__ bgo,
    const float* __restrict__ bff, float* __restrict__ bias_c,
    const u16* __restrict__ qkvl, u16* __restrict__ attn_l)
{
  __shared__ __align__(16) u16 smem[20480];  // 40 KB
  const int bx   = blockIdx.x;
  const int tid  = threadIdx.x;
  const int lane = tid & 63;
  const int w    = tid >> 6;

  if (bx >= 1064) {               // ---- local banded attention (|i-j|<=3) ----
    const int lbx = bx - 1064;
    const int qt = lbx & 15, bh = lbx >> 4;
    const int b = bh >> 3, h = bh & 7;
    const int i0 = qt * 64;
    const size_t base = (size_t)b * 1024 * 1536;
    u16* Kl = smem;                // 70 rows x stride 72
    u16* Vl = smem + 5040;

    for (int i2 = tid; i2 < 1120; i2 += 256) {
      const int isV = i2 >= 560;
      const int i3  = isV ? i2 - 560 : i2;
      const int row = i3 >> 3, ch = i3 & 7;
      const int jc = min(max(i0 - 3 + row, 0), 1023);
      const ui4 d = *reinterpret_cast<const ui4*>(
          qkvl + base + (size_t)jc * 1536 + (isV ? 1024 : 512) + h * 64 + ch * 8);
      *reinterpret_cast<ui4*>(&(isV ? Vl : Kl)[row * 72 + ch * 8]) = d;
    }
    __syncthreads();

    const int q   = lane >> 2;     // 0..15 query within wave
    const int oct = lane & 3;      // 16-wide dh slice
    const int i   = i0 + w * 16 + q;
    const u16* qrow = qkvl + base + (size_t)i * 1536 + h * 64 + oct * 16;
    float qf[16];
    {
      const v8bf q0 = *reinterpret_cast<const v8bf*>(qrow);
      const v8bf q1 = *reinterpret_cast<const v8bf*>(qrow + 8);
#pragma unroll
      for (int e = 0; e < 8; ++e) { qf[e] = (float)q0[e]; qf[8 + e] = (float)q1[e]; }
    }
    float denom = 0.f, accv[16];
#pragma unroll
    for (int e = 0; e < 16; ++e) accv[e] = 0.f;

#pragma unroll
    for (int tt = 0; tt < 7; ++tt) {
      const int j = i - 3 + tt;
      const bool ok = (j >= 0) && (j <= 1023);
      const int ridx = w * 16 + q + tt;
      const v8bf k0 = *reinterpret_cast<const v8bf*>(&Kl[ridx * 72 + oct * 16]);
      const v8bf k1 = *reinterpret_cast<const v8bf*>(&Kl[ridx * 72 + oct * 16 + 8]);
      float pr = 0.f;
#pragma unroll
      for (int e = 0; e < 8; ++e)
        pr += qf[e] * (float)k0[e] + qf[8 + e] * (float)k1[e];
      pr += __shfl_xor(pr, 1);     // reduce across the 4 oct lanes
      pr += __shfl_xor(pr, 2);
      const float p = ok ? __expf(pr * 0.125f) : 0.f;
      denom += p;
      const v8bf v0 = *reinterpret_cast<const v8bf*>(&Vl[ridx * 72 + oct * 16]);
      const v8bf v1 = *reinterpret_cast<const v8bf*>(&Vl[ridx * 72 + oct * 16 + 8]);
#pragma unroll
      for (int e = 0; e < 8; ++e) {
        accv[e]     += p * (float)v0[e];
        accv[8 + e] += p * (float)v1[e];
      }
    }
    const float inv = 1.f / denom;
    u16* dst = attn_l + (size_t)(b * 1024 + i) * 1536 + h * 64 + oct * 16;
#pragma unroll
    for (int c4 = 0; c4 < 4; ++c4) {
      us4 pk;
#pragma unroll
      for (int e = 0; e < 4; ++e) pk[e] = f2bf(accv[c4 * 4 + e] * inv);
      *reinterpret_cast<us4*>(dst + c4 * 4) = pk;
    }
    return;
  }
  if (bx >= 1056) {               // ---- bias_c[e] = bf[e] + Wf[e,:].bcat ----
    const int e = (bx - 1056) * 64 + w * 16;
    for (int t = 0; t < 16; ++t) {
      float sum = 0.f;
#pragma unroll
      for (int j = 0; j < 16; ++j) {
        const int c2 = j * 64 + lane;
        const float b = (c2 < 512) ? blo[c2] : bgo[c2 - 512];
        sum += bf2f(wfb[(size_t)(e + t) * 1024 + c2]) * b;
      }
#pragma unroll
      for (int msk = 32; msk >= 1; msk >>= 1) sum += __shfl_xor(sum, msk);
      if (lane == 0) bias_c[e + t] = bff[e + t] + sum;
    }
    return;
  }
  if (bx >= 1024) {               // ---- Wc[e][half*512+k] = Wf_half @ WxT ----
    const int idx = bx - 1024;
    const int half = idx >> 4, rem = idx & 15;
    gemm_body<0,0,0,0>(smem, smem + 8192, wfb + half * 512, 1024,
                       (half ? wgoT : wloT), 512, nullptr, Wc, nullptr,
                       (rem >> 2) * 128, (rem & 3) * 128, 512, 1024, half * 512);
    return;
  }

  // ---- flash attention (DMA-staged dbuf, source-XOR swizzle, fixed-base) ----
  const int lid  = lane & 15;
  const int quad = lane >> 4;
  const int qt = (bx >> 3) & 15;                    // XCD-aware: all 16 qt of a
  const int bh = ((bx & 7) << 3) | (bx >> 7);       // head on one XCD
  const int b = bh >> 3, h = bh & 7;
  const size_t base = (size_t)b * 1024 * 1536;

  v8bf aq[2];
  {
    const size_t qoff = base + (size_t)(qt * 64 + w * 16 + lid) * 1536 + h * 64 + quad * 8;
    aq[0] = *reinterpret_cast<const v8bf*>(qkv + qoff);
    aq[1] = *reinterpret_cast<const v8bf*>(qkv + qoff + 32);
#pragma unroll
    for (int k = 0; k < 2; ++k)
#pragma unroll
      for (int i = 0; i < 8; ++i)
        aq[k][i] = (__bf16)((float)aq[k][i] * 0.125f);  // exact
  }
  v8bf ones;
#pragma unroll
  for (int i = 0; i < 8; ++i) ones[i] = (__bf16)1.0f;

  v4f o[4], lacc = (v4f){0.f, 0.f, 0.f, 0.f};
#pragma unroll
  for (int nd = 0; nd < 4; ++nd) o[nd] = (v4f){0.f, 0.f, 0.f, 0.f};

  u16* Ps = smem + 16384;
  const int dr = lane >> 3;
  const int dc = lane & 7;
#define STAGE(KT, BI)                                                          \
  {                                                                            \
    _Pragma("unroll") for (int p = 0; p < 2; ++p) {                            \
      const int r = (w + p * 4) * 8 + dr;                                      \
      const int cs = (dc ^ (r & 7)) * 8;                                       \
      load_lds16(qkv + base + (size_t)((KT) * 64 + r) * 1536 + 512 + h * 64 + cs, \
                 smem + (BI) * 4096 + (w + p * 4) * 512);                      \
      load_lds16(vt + ((size_t)bh * 64 + r) * 1024 + (KT) * 64 + cs,           \
                 smem + 8192 + (BI) * 4096 + (w + p * 4) * 512);               \
    }                                                                          \
  }
  STAGE(0, 0);

  for (int kt = 0; kt < 16; ++kt) {
    __syncthreads();
    if (kt < 15) STAGE(kt + 1, (kt + 1) & 1);
    const u16* Ks = smem + (kt & 1) * 4096;
    const u16* Vs = smem + 8192 + (kt & 1) * 4096;

    v4f s[4];
#pragma unroll
    for (int nk = 0; nk < 4; ++nk) s[nk] = (v4f){0.f, 0.f, 0.f, 0.f};
#pragma unroll
    for (int kk = 0; kk < 2; ++kk)
#pragma unroll
      for (int nk = 0; nk < 4; ++nk) {
        const v8bf bk = *reinterpret_cast<const v8bf*>(
            &Ks[(nk * 16 + lid) * 64 + (((kk * 4 + quad) ^ (lid & 7)) * 8)]);
        s[nk] = __builtin_amdgcn_mfma_f32_16x16x32_bf16(aq[kk], bk, s[nk], 0, 0, 0);
      }

#pragma unroll
    for (int nk = 0; nk < 4; ++nk) {
#pragma unroll
      for (int r = 0; r < 4; ++r) {
        const float p = __expf(s[nk][r]);
        const int prow = quad * 4 + r;
        const int pcol = nk * 16 + lid;
        // truncated bf16 (ds_write_b16_d16_hi) — l sums the same truncation
        Ps[w * 1024 + prow * 64 + (((pcol >> 3) ^ (prow & 7)) * 8) + (pcol & 7)] =
            (u16)(__builtin_bit_cast(u32, p) >> 16);
      }
    }

    // O^T = V^T P^T
#pragma unroll
    for (int kk = 0; kk < 2; ++kk) {
      const v8bf ap = *reinterpret_cast<const v8bf*>(
          &Ps[w * 1024 + lid * 64 + (((kk * 4 + quad) ^ (lid & 7)) * 8)]);
      lacc = __builtin_amdgcn_mfma_f32_16x16x32_bf16(ones, ap, lacc, 0, 0, 0);
#pragma unroll
      for (int nd = 0; nd < 4; ++nd) {
        const v8bf av = *reinterpret_cast<const v8bf*>(
            &Vs[(nd * 16 + lid) * 64 + (((kk * 4 + quad) ^ (lid & 7)) * 8)]);
        o[nd] = __builtin_amdgcn_mfma_f32_16x16x32_bf16(av, ap, o[nd], 0, 0, 0);
      }
    }
  }
#undef STAGE

  const float inv = 1.f / lacc[0];
  const int tok = b * 1024 + qt * 64 + w * 16 + lid;
#pragma unroll
  for (int nd = 0; nd < 4; ++nd) {
    us4 pk;
#pragma unroll
    for (int r = 0; r < 4; ++r) pk[r] = f2bf(o[nd][r] * inv);
    *reinterpret_cast<us4*>(&outp[(size_t)tok * 512 + h * 64 + nd * 16 + quad * 4]) = pk;
  }
}

// ---------------------------------------------------------------------------
// Final fused GEMM: out = ReLU([attn_l|attn_g] @ Wc^T + bias_c), fp32 out.
// attn_l lives in qkv_g's V-slots (lda 1536); attn_g is dense (lda 512).
// ---------------------------------------------------------------------------
__global__ void __launch_bounds__(256) gemm_final(
    const u16* __restrict__ Al, const u16* __restrict__ Ag,
    const u16* __restrict__ Bw, const float* __restrict__ biasc,
    float* __restrict__ out)
{
  __shared__ __align__(16) u16 As[64 * 64];
  __shared__ __align__(16) u16 Bs[128 * 64];
  const int tid  = threadIdx.x;
  const int lane = tid & 63;
  const int w    = tid >> 6;
  const int lid  = lane & 15;
  const int quad = lane >> 4;
  const int bm = blockIdx.y * 64;
  const int bn = blockIdx.x * 128;

  v4f acc[4][2];
#pragma unroll
  for (int i = 0; i < 4; ++i)
#pragma unroll
    for (int j = 0; j < 2; ++j)
      acc[i][j] = (v4f){0.f, 0.f, 0.f, 0.f};

  const int dr = lane >> 3;
  const int cs = ((lane ^ dr) & 7) * 8;

  for (int k0 = 0; k0 < 1024; k0 += 64) {
    const int half = k0 >> 9;
    const u16* Asrc = half ? Ag : Al;
    const int  lda  = half ? 512 : 1536;
    const int  kcol = k0 & 511;
#pragma unroll
    for (int p = 0; p < 2; ++p) {
      const int g   = w + p * 4;
      const int row = g * 8 + dr;
      load_lds16(Asrc + (size_t)(bm + row) * lda + kcol + cs, As + g * 512);
    }
#pragma unroll
    for (int p = 0; p < 4; ++p) {
      const int g   = w + p * 4;
      const int row = g * 8 + dr;
      load_lds16(Bw + (size_t)(bn + row) * 1024 + k0 + cs, Bs + g * 512);
    }
    __syncthreads();
#pragma unroll
    for (int kk = 0; kk < 2; ++kk) {
      v8bf af[4], bfr[2];
#pragma unroll
      for (int mi = 0; mi < 4; ++mi)
        af[mi] = *reinterpret_cast<const v8bf*>(
            &As[(mi * 16 + lid) * 64 + (((kk * 4 + quad) ^ (lid & 7)) * 8)]);
#pragma unroll
      for (int ni = 0; ni < 2; ++ni)
        bfr[ni] = *reinterpret_cast<const v8bf*>(
            &Bs[(w * 32 + ni * 16 + lid) * 64 + (((kk * 4 + quad) ^ (lid & 7)) * 8)]);
#pragma unroll
      for (int mi = 0; mi < 4; ++mi)
#pragma unroll
        for (int ni = 0; ni < 2; ++ni)
          acc[mi][ni] = __builtin_amdgcn_mfma_f32_16x16x32_bf16(
              af[mi], bfr[ni], acc[mi][ni], 0, 0, 0);
    }
    __syncthreads();
  }

#pragma unroll
  for (int mi = 0; mi < 4; ++mi) {
#pragma unroll
    for (int ni = 0; ni < 2; ++ni) {
      const int n = bn + w * 32 + ni * 16 + lid;
      const float bv = biasc[n];
#pragma unroll
      for (int r = 0; r < 4; ++r) {
        const int m = bm + mi * 16 + quad * 4 + r;
        out[(size_t)m * 512 + n] = fmaxf(acc[mi][ni][r] + bv, 0.f);
      }
    }
  }
}

// ---------------------------------------------------------------------------
// Workspace (u16 elems), total 36701184 = 73.4 MB:
//   0        xb (dead after qkv_dual -> attn_g) | 4194304 wli | 4980736 wgi
//   5767168  wfb | 6291456 qkv_l | 18874368 qkv_g (V-thirds = attn_l)
//   31457280 vt | 35651584 Wc | 36175872 bias_c | 36176896 wloT | 36439040 wgoT
// ---------------------------------------------------------------------------
extern "C" void kernel_launch(void* const* d_in, const int* in_sizes, int n_in,
                              void* d_out, int out_size, void* d_ws, size_t ws_size,
                              hipStream_t stream) {
  (void)in_sizes; (void)n_in; (void)out_size; (void)ws_size;
  const float* x   = (const float*)d_in[0];
  const float* Wli = (const float*)d_in[1];
  const float* bli = (const float*)d_in[2];
  const float* Wlo = (const float*)d_in[3];
  const float* blo = (const float*)d_in[4];
  const float* Wgi = (const float*)d_in[5];
  const float* bgi = (const float*)d_in[6];
  const float* Wgo = (const float*)d_in[7];
  const float* bgo = (const float*)d_in[8];
  const float* Wf  = (const float*)d_in[9];
  const float* bff = (const float*)d_in[10];
  float* out = (float*)d_out;

  u16* W      = (u16*)d_ws;
  u16* xb     = W + 0;
  u16* wli    = W + 4194304;
  u16* wgi    = W + 4980736;
  u16* wfb    = W + 5767168;
  u16* qkv_l  = W + 6291456;
  u16* qkv_g  = W + 18874368;
  u16* vt     = W + 31457280;
  u16* Wc     = W + 35651584;
  float* bias_c = (float*)(W + 36175872);
  u16* wloT   = W + 36176896;
  u16* wgoT   = W + 36439040;
  u16* attn_g = W + 0;                  // over dead xb
  u16* attn_l = qkv_g + 1024;           // dead V-thirds of qkv_g, lda 1536

  cvt_all<<<6656, 256, 0, stream>>>(x, Wli, Wlo, Wgi, Wgo, Wf, W, wloT, wgoT);
  qkv_dual<<<dim3(24, 64), 256, 0, stream>>>(xb, wli, bli, qkv_l, wgi, bgi, qkv_g, vt);
  mega<<<2088, 256, 0, stream>>>(qkv_g, vt, attn_g, wfb, wloT, wgoT, Wc,
                                 blo, bgo, bff, bias_c, qkv_l, attn_l);
  gemm_final<<<dim3(4, 128), 256, 0, stream>>>(attn_l, attn_g, Wc, bias_c, out);
}

// Round 8
// 180.620 us; speedup vs baseline: 1.2205x; 1.0110x over previous
//
#include <hip/hip_runtime.h>

typedef unsigned short u16;
typedef unsigned int   u32;
typedef __bf16 v8bf __attribute__((ext_vector_type(8)));
typedef float  v4f  __attribute__((ext_vector_type(4)));
typedef u16    us4  __attribute__((ext_vector_type(4)));
typedef u32    ui4  __attribute__((ext_vector_type(4)));

__device__ __forceinline__ u16 f2bf(float f) {
  u32 u = __builtin_bit_cast(u32, f);
  u += 0x7fffu + ((u >> 16) & 1u);   // RNE
  return (u16)(u >> 16);
}
__device__ __forceinline__ float bf2f(u16 s) {
  u32 u = ((u32)s) << 16;
  return __builtin_bit_cast(float, u);
}

// 16B async global->LDS DMA; LDS dest = wave-uniform base + lane*16 (m97).
__device__ __forceinline__ void load_lds16(const u16* g, u16* l) {
  __builtin_amdgcn_global_load_lds(
      (const __attribute__((address_space(1))) u32*)g,
      (__attribute__((address_space(3))) u32*)l, 16, 0, 0);
}

// ---------------------------------------------------------------------------
// fp32 -> bf16 of x, Wl_in, Wg_in, Wf (flat) and Wl_out/Wg_out (TRANSPOSED).
// ---------------------------------------------------------------------------
__global__ void __launch_bounds__(256) cvt_all(
    const float* __restrict__ x,   const float* __restrict__ wli,
    const float* __restrict__ wlo, const float* __restrict__ wgi,
    const float* __restrict__ wgo, const float* __restrict__ wf,
    u16* __restrict__ out, u16* __restrict__ wloT, u16* __restrict__ wgoT)
{
  const int v = blockIdx.x * 256 + threadIdx.x;  // < 1703936
  const float* src; int obase; int mode = 0; u16* T = nullptr;
  if      (v < 1048576) { src = x;   obase = 0;       }
  else if (v < 1245184) { src = wli; obase = 1048576; }
  else if (v < 1310720) { src = wlo; obase = 1245184; mode = 1; T = wloT; }
  else if (v < 1507328) { src = wgi; obase = 1310720; }
  else if (v < 1572864) { src = wgo; obase = 1507328; mode = 1; T = wgoT; }
  else                  { src = wf;  obase = 1572864; }
  const int rel = v - obase;
  const float4 f = reinterpret_cast<const float4*>(src)[rel];
  us4 o;
  o.x = f2bf(f.x); o.y = f2bf(f.y); o.z = f2bf(f.z); o.w = f2bf(f.w);
  if (mode) {
    const int eb = rel * 4, c = eb >> 9, k = eb & 511;
#pragma unroll
    for (int i = 0; i < 4; ++i) T[(k + i) * 512 + c] = o[i];
  } else {
    int o4;
    if      (v < 1245184) o4 = v;            // xb | wli contiguous
    else if (v < 1507328) o4 = v - 65536;    // wgi
    else                  o4 = v - 131072;   // wfb
    reinterpret_cast<us4*>(out)[o4] = o;
  }
}

// ---------------------------------------------------------------------------
// bf16 NT GEMM body, 128x128 tile, BK=64, global_load_lds staging (m97) with
// SOURCE-XOR swizzle (conflict-free b128 fragment reads).
// ---------------------------------------------------------------------------
template<int RELU, int OUTF32, int TV, int BIASF>
__device__ __forceinline__ void gemm_body(
    u16* __restrict__ As, u16* __restrict__ Bs,
    const u16* __restrict__ A, const int lda,
    const u16* __restrict__ B, const int ldb,
    const float* __restrict__ bias, void* __restrict__ C,
    u16* __restrict__ vt, const int bm, const int bn,
    const int K, const int ldc, const int colofs)
{
  const int tid  = threadIdx.x;
  const int lane = tid & 63;
  const int w    = tid >> 6;
  const int lid  = lane & 15;
  const int quad = lane >> 4;
  const int wr = w >> 1, wc = w & 1;

  v4f acc[4][4];
#pragma unroll
  for (int i = 0; i < 4; ++i)
#pragma unroll
    for (int j = 0; j < 4; ++j)
      acc[i][j] = (v4f){0.f, 0.f, 0.f, 0.f};

  const int dr = lane >> 3;              // row within 8-row DMA group
  const int cs = ((lane ^ dr) & 7) * 8;  // source chunk = dc ^ dr (swizzle)

  for (int k0 = 0; k0 < K; k0 += 64) {
#pragma unroll
    for (int p = 0; p < 4; ++p) {
      const int g   = w + p * 4;
      const int row = g * 8 + dr;
      load_lds16(A + (size_t)(bm + row) * lda + k0 + cs, As + g * 512);
      load_lds16(B + (size_t)(bn + row) * ldb + k0 + cs, Bs + g * 512);
    }
    __syncthreads();
#pragma unroll
    for (int kk = 0; kk < 2; ++kk) {
      v8bf af[4], bfr[4];
#pragma unroll
      for (int mi = 0; mi < 4; ++mi)
        af[mi] = *reinterpret_cast<const v8bf*>(
            &As[(wr * 64 + mi * 16 + lid) * 64 + (((kk * 4 + quad) ^ (lid & 7)) * 8)]);
#pragma unroll
      for (int ni = 0; ni < 4; ++ni)
        bfr[ni] = *reinterpret_cast<const v8bf*>(
            &Bs[(wc * 64 + ni * 16 + lid) * 64 + (((kk * 4 + quad) ^ (lid & 7)) * 8)]);
#pragma unroll
      for (int mi = 0; mi < 4; ++mi)
#pragma unroll
        for (int ni = 0; ni < 4; ++ni)
          acc[mi][ni] = __builtin_amdgcn_mfma_f32_16x16x32_bf16(
              af[mi], bfr[ni], acc[mi][ni], 0, 0, 0);
    }
    __syncthreads();
  }

  float bv[4];
#pragma unroll
  for (int ni = 0; ni < 4; ++ni)
    bv[ni] = BIASF ? bias[bn + wc * 64 + ni * 16 + lid] : 0.f;

  if (TV && bn >= 1024) {
#pragma unroll
    for (int mi = 0; mi < 4; ++mi) {
      const int m0 = bm + wr * 64 + mi * 16 + quad * 4;
#pragma unroll
      for (int ni = 0; ni < 4; ++ni) {
        const int n = bn + wc * 64 + ni * 16 + lid - 1024;  // 0..511 = (h,d)
        us4 pk;
#pragma unroll
        for (int r = 0; r < 4; ++r) pk[r] = f2bf(acc[mi][ni][r] + bv[ni]);
        const size_t idx =
            ((size_t)((m0 >> 10) * 8 + (n >> 6)) * 64 + (n & 63)) * 1024 + (m0 & 1023);
        *reinterpret_cast<us4*>(&vt[idx]) = pk;
      }
    }
  } else {
#pragma unroll
    for (int mi = 0; mi < 4; ++mi) {
#pragma unroll
      for (int ni = 0; ni < 4; ++ni) {
        const int n = bn + wc * 64 + ni * 16 + lid;
#pragma unroll
        for (int r = 0; r < 4; ++r) {
          const int m = bm + wr * 64 + mi * 16 + quad * 4 + r;
          float v = acc[mi][ni][r] + bv[ni];
          if (RELU) v = fmaxf(v, 0.f);
          if (OUTF32)
            reinterpret_cast<float*>(C)[(size_t)m * ldc + colofs + n] = v;
          else
            reinterpret_cast<u16*>(C)[(size_t)m * ldc + colofs + n] = f2bf(v);
        }
      }
    }
  }
}

// Both QKV projections, one launch. bx<12: local set; else global set (+TV).
__global__ void __launch_bounds__(256) qkv_dual(
    const u16* __restrict__ xb,
    const u16* __restrict__ wli, const float* __restrict__ bli, u16* __restrict__ qkv_l,
    const u16* __restrict__ wgi, const float* __restrict__ bgi, u16* __restrict__ qkv_g,
    u16* __restrict__ vt)
{
  __shared__ __align__(16) u16 As[128 * 64];
  __shared__ __align__(16) u16 Bs[128 * 64];
  if (blockIdx.x < 12)
    gemm_body<0,0,0,1>(As, Bs, xb, 512, wli, 512, bli, qkv_l, nullptr,
                       blockIdx.y * 128, blockIdx.x * 128, 512, 1536, 0);
  else
    gemm_body<0,0,1,1>(As, Bs, xb, 512, wgi, 512, bgi, qkv_g, vt,
                       blockIdx.y * 128, (blockIdx.x - 12) * 128, 512, 1536, 0);
}

// ---------------------------------------------------------------------------
// MEGA:
//   bx <  512 : flash-attention, 128-QUERY tiles (r8): each wave owns 32
//               queries (2 query-sets). K/V fragments are loaded ONCE into
//               registers per kt and reused across both query-sets:
//               per-128q-per-kt ds_read_b128 36->20, barriers halved,
//               MFMA count unchanged. XCD pinning kept (KV set 2 MB/XCD).
//   512..543  : weight-combine GEMMs (Wc = Wf_half @ WxT)
//   544..551  : combined-bias reduction
//   552..1575 : local banded attention (r7 re-parallelized layout)
// ---------------------------------------------------------------------------
__global__ void __launch_bounds__(256, 3) mega(
    const u16* __restrict__ qkv, const u16* __restrict__ vt, u16* __restrict__ outp,
    const u16* __restrict__ wfb, const u16* __restrict__ wloT, const u16* __restrict__ wgoT,
    u16* __restrict__ Wc, const float* __restrict__ blo, const float* __restrict__ bgo,
    const float* __restrict__ bff, float* __restrict__ bias_c,
    const u16* __restrict__ qkvl, u16* __restrict__ attn_l)
{
  __shared__ __align__(16) u16 smem[24576];  // 48 KB
  const int bx   = blockIdx.x;
  const int tid  = threadIdx.x;
  const int lane = tid & 63;
  const int w    = tid >> 6;

  if (bx >= 552) {                // ---- local banded attention (|i-j|<=3) ----
    const int lbx = bx - 552;
    const int qt = lbx & 15, bh = lbx >> 4;
    const int b = bh >> 3, h = bh & 7;
    const int i0 = qt * 64;
    const size_t base = (size_t)b * 1024 * 1536;
    u16* Kl = smem;                // 70 rows x stride 72
    u16* Vl = smem + 5040;

    for (int i2 = tid; i2 < 1120; i2 += 256) {
      const int isV = i2 >= 560;
      const int i3  = isV ? i2 - 560 : i2;
      const int row = i3 >> 3, ch = i3 & 7;
      const int jc = min(max(i0 - 3 + row, 0), 1023);
      const ui4 d = *reinterpret_cast<const ui4*>(
          qkvl + base + (size_t)jc * 1536 + (isV ? 1024 : 512) + h * 64 + ch * 8);
      *reinterpret_cast<ui4*>(&(isV ? Vl : Kl)[row * 72 + ch * 8]) = d;
    }
    __syncthreads();

    const int q   = lane >> 2;     // 0..15 query within wave
    const int oct = lane & 3;      // 16-wide dh slice
    const int i   = i0 + w * 16 + q;
    const u16* qrow = qkvl + base + (size_t)i * 1536 + h * 64 + oct * 16;
    float qf[16];
    {
      const v8bf q0 = *reinterpret_cast<const v8bf*>(qrow);
      const v8bf q1 = *reinterpret_cast<const v8bf*>(qrow + 8);
#pragma unroll
      for (int e = 0; e < 8; ++e) { qf[e] = (float)q0[e]; qf[8 + e] = (float)q1[e]; }
    }
    float denom = 0.f, accv[16];
#pragma unroll
    for (int e = 0; e < 16; ++e) accv[e] = 0.f;

#pragma unroll
    for (int tt = 0; tt < 7; ++tt) {
      const int j = i - 3 + tt;
      const bool ok = (j >= 0) && (j <= 1023);
      const int ridx = w * 16 + q + tt;
      const v8bf k0 = *reinterpret_cast<const v8bf*>(&Kl[ridx * 72 + oct * 16]);
      const v8bf k1 = *reinterpret_cast<const v8bf*>(&Kl[ridx * 72 + oct * 16 + 8]);
      float pr = 0.f;
#pragma unroll
      for (int e = 0; e < 8; ++e)
        pr += qf[e] * (float)k0[e] + qf[8 + e] * (float)k1[e];
      pr += __shfl_xor(pr, 1);     // reduce across the 4 oct lanes
      pr += __shfl_xor(pr, 2);
      const float p = ok ? __expf(pr * 0.125f) : 0.f;
      denom += p;
      const v8bf v0 = *reinterpret_cast<const v8bf*>(&Vl[ridx * 72 + oct * 16]);
      const v8bf v1 = *reinterpret_cast<const v8bf*>(&Vl[ridx * 72 + oct * 16 + 8]);
#pragma unroll
      for (int e = 0; e < 8; ++e) {
        accv[e]     += p * (float)v0[e];
        accv[8 + e] += p * (float)v1[e];
      }
    }
    const float inv = 1.f / denom;
    u16* dst = attn_l + (size_t)(b * 1024 + i) * 1536 + h * 64 + oct * 16;
#pragma unroll
    for (int c4 = 0; c4 < 4; ++c4) {
      us4 pk;
#pragma unroll
      for (int e = 0; e < 4; ++e) pk[e] = f2bf(accv[c4 * 4 + e] * inv);
      *reinterpret_cast<us4*>(dst + c4 * 4) = pk;
    }
    return;
  }
  if (bx >= 544) {                // ---- bias_c[e] = bf[e] + Wf[e,:].bcat ----
    const int e = (bx - 544) * 64 + w * 16;
    for (int t = 0; t < 16; ++t) {
      float sum = 0.f;
#pragma unroll
      for (int j = 0; j < 16; ++j) {
        const int c2 = j * 64 + lane;
        const float b = (c2 < 512) ? blo[c2] : bgo[c2 - 512];
        sum += bf2f(wfb[(size_t)(e + t) * 1024 + c2]) * b;
      }
#pragma unroll
      for (int msk = 32; msk >= 1; msk >>= 1) sum += __shfl_xor(sum, msk);
      if (lane == 0) bias_c[e + t] = bff[e + t] + sum;
    }
    return;
  }
  if (bx >= 512) {                // ---- Wc[e][half*512+k] = Wf_half @ WxT ----
    const int idx = bx - 512;
    const int half = idx >> 4, rem = idx & 15;
    gemm_body<0,0,0,0>(smem, smem + 8192, wfb + half * 512, 1024,
                       (half ? wgoT : wloT), 512, nullptr, Wc, nullptr,
                       (rem >> 2) * 128, (rem & 3) * 128, 512, 1024, half * 512);
    return;
  }

  // ---- flash attention: 128-query tile, DMA dbuf, fixed-base softmax ----
  const int lid  = lane & 15;
  const int quad = lane >> 4;
  const int qt = (bx >> 3) & 7;                     // 0..7, 128-query tiles
  const int bh = ((bx & 7) << 3) | (bx >> 6);       // head pinned to XCD=bx&7
  const int b = bh >> 3, h = bh & 7;
  const size_t base = (size_t)b * 1024 * 1536;

  v8bf aq[2][2];
#pragma unroll
  for (int qs = 0; qs < 2; ++qs) {
    const size_t qoff =
        base + (size_t)(qt * 128 + w * 32 + qs * 16 + lid) * 1536 + h * 64 + quad * 8;
    aq[qs][0] = *reinterpret_cast<const v8bf*>(qkv + qoff);
    aq[qs][1] = *reinterpret_cast<const v8bf*>(qkv + qoff + 32);
#pragma unroll
    for (int k = 0; k < 2; ++k)
#pragma unroll
      for (int i = 0; i < 8; ++i)
        aq[qs][k][i] = (__bf16)((float)aq[qs][k][i] * 0.125f);  // exact
  }
  v8bf ones;
#pragma unroll
  for (int i = 0; i < 8; ++i) ones[i] = (__bf16)1.0f;

  v4f o[2][4], lacc[2];
#pragma unroll
  for (int qs = 0; qs < 2; ++qs) {
    lacc[qs] = (v4f){0.f, 0.f, 0.f, 0.f};
#pragma unroll
    for (int nd = 0; nd < 4; ++nd) o[qs][nd] = (v4f){0.f, 0.f, 0.f, 0.f};
  }

  u16* Ps = smem + 16384;          // per-wave 2048 u16 (2 qsets x 16 x 64)
  const int dr = lane >> 3;
  const int dc = lane & 7;
#define STAGE(KT, BI)                                                          \
  {                                                                            \
    _Pragma("unroll") for (int p = 0; p < 2; ++p) {                            \
      const int r = (w + p * 4) * 8 + dr;                                      \
      const int cs = (dc ^ (r & 7)) * 8;                                       \
      load_lds16(qkv + base + (size_t)((KT) * 64 + r) * 1536 + 512 + h * 64 + cs, \
                 smem + (BI) * 4096 + (w + p * 4) * 512);                      \
      load_lds16(vt + ((size_t)bh * 64 + r) * 1024 + (KT) * 64 + cs,           \
                 smem + 8192 + (BI) * 4096 + (w + p * 4) * 512);               \
    }                                                                          \
  }
  STAGE(0, 0);

  for (int kt = 0; kt < 16; ++kt) {
    __syncthreads();
    if (kt < 15) STAGE(kt + 1, (kt + 1) & 1);
    const u16* Ks = smem + (kt & 1) * 4096;
    const u16* Vs = smem + 8192 + (kt & 1) * 4096;

    // K fragments once, reused by both query-sets
    v8bf bk[2][4];
#pragma unroll
    for (int kk = 0; kk < 2; ++kk)
#pragma unroll
      for (int nk = 0; nk < 4; ++nk)
        bk[kk][nk] = *reinterpret_cast<const v8bf*>(
            &Ks[(nk * 16 + lid) * 64 + (((kk * 4 + quad) ^ (lid & 7)) * 8)]);

#pragma unroll
    for (int qs = 0; qs < 2; ++qs) {
      v4f s[4];
#pragma unroll
      for (int nk = 0; nk < 4; ++nk) s[nk] = (v4f){0.f, 0.f, 0.f, 0.f};
#pragma unroll
      for (int kk = 0; kk < 2; ++kk)
#pragma unroll
        for (int nk = 0; nk < 4; ++nk)
          s[nk] = __builtin_amdgcn_mfma_f32_16x16x32_bf16(
              aq[qs][kk], bk[kk][nk], s[nk], 0, 0, 0);
#pragma unroll
      for (int nk = 0; nk < 4; ++nk) {
#pragma unroll
        for (int r = 0; r < 4; ++r) {
          const float p = __expf(s[nk][r]);
          const int prow = quad * 4 + r;
          const int pcol = nk * 16 + lid;
          // truncated bf16 (b16_d16_hi store) — l sums the same truncation
          Ps[w * 2048 + qs * 1024 + prow * 64 +
             (((pcol >> 3) ^ (prow & 7)) * 8) + (pcol & 7)] =
              (u16)(__builtin_bit_cast(u32, p) >> 16);
        }
      }
    }

    // O^T = V^T P^T ; V fragments once, reused by both query-sets
#pragma unroll
    for (int kk = 0; kk < 2; ++kk) {
      v8bf av[4];
#pragma unroll
      for (int nd = 0; nd < 4; ++nd)
        av[nd] = *reinterpret_cast<const v8bf*>(
            &Vs[(nd * 16 + lid) * 64 + (((kk * 4 + quad) ^ (lid & 7)) * 8)]);
#pragma unroll
      for (int qs = 0; qs < 2; ++qs) {
        const v8bf ap = *reinterpret_cast<const v8bf*>(
            &Ps[w * 2048 + qs * 1024 + lid * 64 + (((kk * 4 + quad) ^ (lid & 7)) * 8)]);
        lacc[qs] = __builtin_amdgcn_mfma_f32_16x16x32_bf16(ones, ap, lacc[qs], 0, 0, 0);
#pragma unroll
        for (int nd = 0; nd < 4; ++nd)
          o[qs][nd] = __builtin_amdgcn_mfma_f32_16x16x32_bf16(
              av[nd], ap, o[qs][nd], 0, 0, 0);
      }
    }
  }
#undef STAGE

#pragma unroll
  for (int qs = 0; qs < 2; ++qs) {
    const float inv = 1.f / lacc[qs][0];
    const int tok = b * 1024 + qt * 128 + w * 32 + qs * 16 + lid;
#pragma unroll
    for (int nd = 0; nd < 4; ++nd) {
      us4 pk;
#pragma unroll
      for (int r = 0; r < 4; ++r) pk[r] = f2bf(o[qs][nd][r] * inv);
      *reinterpret_cast<us4*>(
          &outp[(size_t)tok * 512 + h * 64 + nd * 16 + quad * 4]) = pk;
    }
  }
}

// ---------------------------------------------------------------------------
// Final fused GEMM: out = ReLU([attn_l|attn_g] @ Wc^T + bias_c), fp32 out.
// attn_l lives in qkv_g's V-slots (lda 1536); attn_g is dense (lda 512).
// ---------------------------------------------------------------------------
__global__ void __launch_bounds__(256) gemm_final(
    const u16* __restrict__ Al, const u16* __restrict__ Ag,
    const u16* __restrict__ Bw, const float* __restrict__ biasc,
    float* __restrict__ out)
{
  __shared__ __align__(16) u16 As[64 * 64];
  __shared__ __align__(16) u16 Bs[128 * 64];
  const int tid  = threadIdx.x;
  const int lane = tid & 63;
  const int w    = tid >> 6;
  const int lid  = lane & 15;
  const int quad = lane >> 4;
  const int bm = blockIdx.y * 64;
  const int bn = blockIdx.x * 128;

  v4f acc[4][2];
#pragma unroll
  for (int i = 0; i < 4; ++i)
#pragma unroll
    for (int j = 0; j < 2; ++j)
      acc[i][j] = (v4f){0.f, 0.f, 0.f, 0.f};

  const int dr = lane >> 3;
  const int cs = ((lane ^ dr) & 7) * 8;

  for (int k0 = 0; k0 < 1024; k0 += 64) {
    const int half = k0 >> 9;
    const u16* Asrc = half ? Ag : Al;
    const int  lda  = half ? 512 : 1536;
    const int  kcol = k0 & 511;
#pragma unroll
    for (int p = 0; p < 2; ++p) {
      const int g   = w + p * 4;
      const int row = g * 8 + dr;
      load_lds16(Asrc + (size_t)(bm + row) * lda + kcol + cs, As + g * 512);
    }
#pragma unroll
    for (int p = 0; p < 4; ++p) {
      const int g   = w + p * 4;
      const int row = g * 8 + dr;
      load_lds16(Bw + (size_t)(bn + row) * 1024 + k0 + cs, Bs + g * 512);
    }
    __syncthreads();
#pragma unroll
    for (int kk = 0; kk < 2; ++kk) {
      v8bf af[4], bfr[2];
#pragma unroll
      for (int mi = 0; mi < 4; ++mi)
        af[mi] = *reinterpret_cast<const v8bf*>(
            &As[(mi * 16 + lid) * 64 + (((kk * 4 + quad) ^ (lid & 7)) * 8)]);
#pragma unroll
      for (int ni = 0; ni < 2; ++ni)
        bfr[ni] = *reinterpret_cast<const v8bf*>(
            &Bs[(w * 32 + ni * 16 + lid) * 64 + (((kk * 4 + quad) ^ (lid & 7)) * 8)]);
#pragma unroll
      for (int mi = 0; mi < 4; ++mi)
#pragma unroll
        for (int ni = 0; ni < 2; ++ni)
          acc[mi][ni] = __builtin_amdgcn_mfma_f32_16x16x32_bf16(
              af[mi], bfr[ni], acc[mi][ni], 0, 0, 0);
    }
    __syncthreads();
  }

#pragma unroll
  for (int mi = 0; mi < 4; ++mi) {
#pragma unroll
    for (int ni = 0; ni < 2; ++ni) {
      const int n = bn + w * 32 + ni * 16 + lid;
      const float bv = biasc[n];
#pragma unroll
      for (int r = 0; r < 4; ++r) {
        const int m = bm + mi * 16 + quad * 4 + r;
        out[(size_t)m * 512 + n] = fmaxf(acc[mi][ni][r] + bv, 0.f);
      }
    }
  }
}

// ---------------------------------------------------------------------------
// Workspace (u16 elems), total 36701184 = 73.4 MB:
//   0        xb (dead after qkv_dual -> attn_g) | 4194304 wli | 4980736 wgi
//   5767168  wfb | 6291456 qkv_l | 18874368 qkv_g (V-thirds = attn_l)
//   31457280 vt | 35651584 Wc | 36175872 bias_c | 36176896 wloT | 36439040 wgoT
// ---------------------------------------------------------------------------
extern "C" void kernel_launch(void* const* d_in, const int* in_sizes, int n_in,
                              void* d_out, int out_size, void* d_ws, size_t ws_size,
                              hipStream_t stream) {
  (void)in_sizes; (void)n_in; (void)out_size; (void)ws_size;
  const float* x   = (const float*)d_in[0];
  const float* Wli = (const float*)d_in[1];
  const float* bli = (const float*)d_in[2];
  const float* Wlo = (const float*)d_in[3];
  const float* blo = (const float*)d_in[4];
  const float* Wgi = (const float*)d_in[5];
  const float* bgi = (const float*)d_in[6];
  const float* Wgo = (const float*)d_in[7];
  const float* bgo = (const float*)d_in[8];
  const float* Wf  = (const float*)d_in[9];
  const float* bff = (const float*)d_in[10];
  float* out = (float*)d_out;

  u16* W      = (u16*)d_ws;
  u16* xb     = W + 0;
  u16* wli    = W + 4194304;
  u16* wgi    = W + 4980736;
  u16* wfb    = W + 5767168;
  u16* qkv_l  = W + 6291456;
  u16* qkv_g  = W + 18874368;
  u16* vt     = W + 31457280;
  u16* Wc     = W + 35651584;
  float* bias_c = (float*)(W + 36175872);
  u16* wloT   = W + 36176896;
  u16* wgoT   = W + 36439040;
  u16* attn_g = W + 0;                  // over dead xb
  u16* attn_l = qkv_g + 1024;           // dead V-thirds of qkv_g, lda 1536

  cvt_all<<<6656, 256, 0, stream>>>(x, Wli, Wlo, Wgi, Wgo, Wf, W, wloT, wgoT);
  qkv_dual<<<dim3(24, 64), 256, 0, stream>>>(xb, wli, bli, qkv_l, wgi, bgi, qkv_g, vt);
  mega<<<1576, 256, 0, stream>>>(qkv_g, vt, attn_g, wfb, wloT, wgoT, Wc,
                                 blo, bgo, bff, bias_c, qkv_l, attn_l);
  gemm_final<<<dim3(4, 128), 256, 0, stream>>>(attn_l, attn_g, Wc, bias_c, out);
}

// Round 9
// 177.522 us; speedup vs baseline: 1.2418x; 1.0175x over previous
//
#include <hip/hip_runtime.h>

typedef unsigned short u16;
typedef unsigned int   u32;
typedef __bf16 v8bf __attribute__((ext_vector_type(8)));
typedef float  v4f  __attribute__((ext_vector_type(4)));
typedef u16    us4  __attribute__((ext_vector_type(4)));
typedef u32    ui4  __attribute__((ext_vector_type(4)));
typedef u32    ui2  __attribute__((ext_vector_type(2)));

__device__ __forceinline__ u16 f2bf(float f) {
  u32 u = __builtin_bit_cast(u32, f);
  u += 0x7fffu + ((u >> 16) & 1u);   // RNE
  return (u16)(u >> 16);
}
__device__ __forceinline__ float bf2f(u16 s) {
  u32 u = ((u32)s) << 16;
  return __builtin_bit_cast(float, u);
}

// 16B async global->LDS DMA; LDS dest = wave-uniform base + lane*16 (m97).
__device__ __forceinline__ void load_lds16(const u16* g, u16* l) {
  __builtin_amdgcn_global_load_lds(
      (const __attribute__((address_space(1))) u32*)g,
      (__attribute__((address_space(3))) u32*)l, 16, 0, 0);
}

// ---------------------------------------------------------------------------
// fp32 -> bf16 of x, Wl_in, Wg_in, Wf (flat) and Wl_out/Wg_out (TRANSPOSED).
// ---------------------------------------------------------------------------
__global__ void __launch_bounds__(256) cvt_all(
    const float* __restrict__ x,   const float* __restrict__ wli,
    const float* __restrict__ wlo, const float* __restrict__ wgi,
    const float* __restrict__ wgo, const float* __restrict__ wf,
    u16* __restrict__ out, u16* __restrict__ wloT, u16* __restrict__ wgoT)
{
  const int v = blockIdx.x * 256 + threadIdx.x;  // < 1703936
  const float* src; int obase; int mode = 0; u16* T = nullptr;
  if      (v < 1048576) { src = x;   obase = 0;       }
  else if (v < 1245184) { src = wli; obase = 1048576; }
  else if (v < 1310720) { src = wlo; obase = 1245184; mode = 1; T = wloT; }
  else if (v < 1507328) { src = wgi; obase = 1310720; }
  else if (v < 1572864) { src = wgo; obase = 1507328; mode = 1; T = wgoT; }
  else                  { src = wf;  obase = 1572864; }
  const int rel = v - obase;
  const float4 f = reinterpret_cast<const float4*>(src)[rel];
  us4 o;
  o.x = f2bf(f.x); o.y = f2bf(f.y); o.z = f2bf(f.z); o.w = f2bf(f.w);
  if (mode) {
    const int eb = rel * 4, c = eb >> 9, k = eb & 511;
#pragma unroll
    for (int i = 0; i < 4; ++i) T[(k + i) * 512 + c] = o[i];
  } else {
    int o4;
    if      (v < 1245184) o4 = v;            // xb | wli contiguous
    else if (v < 1507328) o4 = v - 65536;    // wgi
    else                  o4 = v - 131072;   // wfb
    reinterpret_cast<us4*>(out)[o4] = o;
  }
}

// ---------------------------------------------------------------------------
// bf16 NT GEMM body, 128x128 tile, BK=64, global_load_lds staging (m97) with
// SOURCE-XOR swizzle (conflict-free b128 fragment reads).
// ---------------------------------------------------------------------------
template<int RELU, int OUTF32, int TV, int BIASF>
__device__ __forceinline__ void gemm_body(
    u16* __restrict__ As, u16* __restrict__ Bs,
    const u16* __restrict__ A, const int lda,
    const u16* __restrict__ B, const int ldb,
    const float* __restrict__ bias, void* __restrict__ C,
    u16* __restrict__ vt, const int bm, const int bn,
    const int K, const int ldc, const int colofs)
{
  const int tid  = threadIdx.x;
  const int lane = tid & 63;
  const int w    = tid >> 6;
  const int lid  = lane & 15;
  const int quad = lane >> 4;
  const int wr = w >> 1, wc = w & 1;

  v4f acc[4][4];
#pragma unroll
  for (int i = 0; i < 4; ++i)
#pragma unroll
    for (int j = 0; j < 4; ++j)
      acc[i][j] = (v4f){0.f, 0.f, 0.f, 0.f};

  const int dr = lane >> 3;              // row within 8-row DMA group
  const int cs = ((lane ^ dr) & 7) * 8;  // source chunk = dc ^ dr (swizzle)

  for (int k0 = 0; k0 < K; k0 += 64) {
#pragma unroll
    for (int p = 0; p < 4; ++p) {
      const int g   = w + p * 4;
      const int row = g * 8 + dr;
      load_lds16(A + (size_t)(bm + row) * lda + k0 + cs, As + g * 512);
      load_lds16(B + (size_t)(bn + row) * ldb + k0 + cs, Bs + g * 512);
    }
    __syncthreads();
#pragma unroll
    for (int kk = 0; kk < 2; ++kk) {
      v8bf af[4], bfr[4];
#pragma unroll
      for (int mi = 0; mi < 4; ++mi)
        af[mi] = *reinterpret_cast<const v8bf*>(
            &As[(wr * 64 + mi * 16 + lid) * 64 + (((kk * 4 + quad) ^ (lid & 7)) * 8)]);
#pragma unroll
      for (int ni = 0; ni < 4; ++ni)
        bfr[ni] = *reinterpret_cast<const v8bf*>(
            &Bs[(wc * 64 + ni * 16 + lid) * 64 + (((kk * 4 + quad) ^ (lid & 7)) * 8)]);
#pragma unroll
      for (int mi = 0; mi < 4; ++mi)
#pragma unroll
        for (int ni = 0; ni < 4; ++ni)
          acc[mi][ni] = __builtin_amdgcn_mfma_f32_16x16x32_bf16(
              af[mi], bfr[ni], acc[mi][ni], 0, 0, 0);
    }
    __syncthreads();
  }

  float bv[4];
#pragma unroll
  for (int ni = 0; ni < 4; ++ni)
    bv[ni] = BIASF ? bias[bn + wc * 64 + ni * 16 + lid] : 0.f;

  if (TV && bn >= 1024) {
#pragma unroll
    for (int mi = 0; mi < 4; ++mi) {
      const int m0 = bm + wr * 64 + mi * 16 + quad * 4;
#pragma unroll
      for (int ni = 0; ni < 4; ++ni) {
        const int n = bn + wc * 64 + ni * 16 + lid - 1024;  // 0..511 = (h,d)
        us4 pk;
#pragma unroll
        for (int r = 0; r < 4; ++r) pk[r] = f2bf(acc[mi][ni][r] + bv[ni]);
        const size_t idx =
            ((size_t)((m0 >> 10) * 8 + (n >> 6)) * 64 + (n & 63)) * 1024 + (m0 & 1023);
        *reinterpret_cast<us4*>(&vt[idx]) = pk;
      }
    }
  } else {
#pragma unroll
    for (int mi = 0; mi < 4; ++mi) {
#pragma unroll
      for (int ni = 0; ni < 4; ++ni) {
        const int n = bn + wc * 64 + ni * 16 + lid;
#pragma unroll
        for (int r = 0; r < 4; ++r) {
          const int m = bm + wr * 64 + mi * 16 + quad * 4 + r;
          float v = acc[mi][ni][r] + bv[ni];
          if (RELU) v = fmaxf(v, 0.f);
          if (OUTF32)
            reinterpret_cast<float*>(C)[(size_t)m * ldc + colofs + n] = v;
          else
            reinterpret_cast<u16*>(C)[(size_t)m * ldc + colofs + n] = f2bf(v);
        }
      }
    }
  }
}

// Both QKV projections, one launch. bx<12: local set; else global set (+TV).
__global__ void __launch_bounds__(256) qkv_dual(
    const u16* __restrict__ xb,
    const u16* __restrict__ wli, const float* __restrict__ bli, u16* __restrict__ qkv_l,
    const u16* __restrict__ wgi, const float* __restrict__ bgi, u16* __restrict__ qkv_g,
    u16* __restrict__ vt)
{
  __shared__ __align__(16) u16 As[128 * 64];
  __shared__ __align__(16) u16 Bs[128 * 64];
  if (blockIdx.x < 12)
    gemm_body<0,0,0,1>(As, Bs, xb, 512, wli, 512, bli, qkv_l, nullptr,
                       blockIdx.y * 128, blockIdx.x * 128, 512, 1536, 0);
  else
    gemm_body<0,0,1,1>(As, Bs, xb, 512, wgi, 512, bgi, qkv_g, vt,
                       blockIdx.y * 128, (blockIdx.x - 12) * 128, 512, 1536, 0);
}

// ---------------------------------------------------------------------------
// MEGA:
//   bx <  512 : flash-attention, 128-query tiles. R9: QK^T computed as
//               S^T = K.Q^T (A/B fragment lane-mappings are identical, so
//               swapping operands is free). S^T C-layout row = KEY, col =
//               query -> the 4 reg values are 4 CONSECUTIVE u16 in the
//               [query][key] Ps buffer: P store = 4 packed ds_write_b64
//               per qset instead of 16 scattered ds_write_b16 (32->8 per kt).
//               Write swizzle 8chunk = (nk*2+(quad>>1))^(lid&7), inner bit
//               quad&1 — matches the existing reader's (kk*4+quad)^(lid&7).
//   512..543  : weight-combine GEMMs (Wc = Wf_half @ WxT)
//   544..551  : combined-bias reduction
//   552..1575 : local banded attention (r7 re-parallelized layout)
// ---------------------------------------------------------------------------
__global__ void __launch_bounds__(256, 3) mega(
    const u16* __restrict__ qkv, const u16* __restrict__ vt, u16* __restrict__ outp,
    const u16* __restrict__ wfb, const u16* __restrict__ wloT, const u16* __restrict__ wgoT,
    u16* __restrict__ Wc, const float* __restrict__ blo, const float* __restrict__ bgo,
    const float* __restrict__ bff, float* __restrict__ bias_c,
    const u16* __restrict__ qkvl, u16* __restrict__ attn_l)
{
  __shared__ __align__(16) u16 smem[24576];  // 48 KB
  const int bx   = blockIdx.x;
  const int tid  = threadIdx.x;
  const int lane = tid & 63;
  const int w    = tid >> 6;

  if (bx >= 552) {                // ---- local banded attention (|i-j|<=3) ----
    const int lbx = bx - 552;
    const int qt = lbx & 15, bh = lbx >> 4;
    const int b = bh >> 3, h = bh & 7;
    const int i0 = qt * 64;
    const size_t base = (size_t)b * 1024 * 1536;
    u16* Kl = smem;                // 70 rows x stride 72
    u16* Vl = smem + 5040;

    for (int i2 = tid; i2 < 1120; i2 += 256) {
      const int isV = i2 >= 560;
      const int i3  = isV ? i2 - 560 : i2;
      const int row = i3 >> 3, ch = i3 & 7;
      const int jc = min(max(i0 - 3 + row, 0), 1023);
      const ui4 d = *reinterpret_cast<const ui4*>(
          qkvl + base + (size_t)jc * 1536 + (isV ? 1024 : 512) + h * 64 + ch * 8);
      *reinterpret_cast<ui4*>(&(isV ? Vl : Kl)[row * 72 + ch * 8]) = d;
    }
    __syncthreads();

    const int q   = lane >> 2;     // 0..15 query within wave
    const int oct = lane & 3;      // 16-wide dh slice
    const int i   = i0 + w * 16 + q;
    const u16* qrow = qkvl + base + (size_t)i * 1536 + h * 64 + oct * 16;
    float qf[16];
    {
      const v8bf q0 = *reinterpret_cast<const v8bf*>(qrow);
      const v8bf q1 = *reinterpret_cast<const v8bf*>(qrow + 8);
#pragma unroll
      for (int e = 0; e < 8; ++e) { qf[e] = (float)q0[e]; qf[8 + e] = (float)q1[e]; }
    }
    float denom = 0.f, accv[16];
#pragma unroll
    for (int e = 0; e < 16; ++e) accv[e] = 0.f;

#pragma unroll
    for (int tt = 0; tt < 7; ++tt) {
      const int j = i - 3 + tt;
      const bool ok = (j >= 0) && (j <= 1023);
      const int ridx = w * 16 + q + tt;
      const v8bf k0 = *reinterpret_cast<const v8bf*>(&Kl[ridx * 72 + oct * 16]);
      const v8bf k1 = *reinterpret_cast<const v8bf*>(&Kl[ridx * 72 + oct * 16 + 8]);
      float pr = 0.f;
#pragma unroll
      for (int e = 0; e < 8; ++e)
        pr += qf[e] * (float)k0[e] + qf[8 + e] * (float)k1[e];
      pr += __shfl_xor(pr, 1);     // reduce across the 4 oct lanes
      pr += __shfl_xor(pr, 2);
      const float p = ok ? __expf(pr * 0.125f) : 0.f;
      denom += p;
      const v8bf v0 = *reinterpret_cast<const v8bf*>(&Vl[ridx * 72 + oct * 16]);
      const v8bf v1 = *reinterpret_cast<const v8bf*>(&Vl[ridx * 72 + oct * 16 + 8]);
#pragma unroll
      for (int e = 0; e < 8; ++e) {
        accv[e]     += p * (float)v0[e];
        accv[8 + e] += p * (float)v1[e];
      }
    }
    const float inv = 1.f / denom;
    u16* dst = attn_l + (size_t)(b * 1024 + i) * 1536 + h * 64 + oct * 16;
#pragma unroll
    for (int c4 = 0; c4 < 4; ++c4) {
      us4 pk;
#pragma unroll
      for (int e = 0; e < 4; ++e) pk[e] = f2bf(accv[c4 * 4 + e] * inv);
      *reinterpret_cast<us4*>(dst + c4 * 4) = pk;
    }
    return;
  }
  if (bx >= 544) {                // ---- bias_c[e] = bf[e] + Wf[e,:].bcat ----
    const int e = (bx - 544) * 64 + w * 16;
    for (int t = 0; t < 16; ++t) {
      float sum = 0.f;
#pragma unroll
      for (int j = 0; j < 16; ++j) {
        const int c2 = j * 64 + lane;
        const float b = (c2 < 512) ? blo[c2] : bgo[c2 - 512];
        sum += bf2f(wfb[(size_t)(e + t) * 1024 + c2]) * b;
      }
#pragma unroll
      for (int msk = 32; msk >= 1; msk >>= 1) sum += __shfl_xor(sum, msk);
      if (lane == 0) bias_c[e + t] = bff[e + t] + sum;
    }
    return;
  }
  if (bx >= 512) {                // ---- Wc[e][half*512+k] = Wf_half @ WxT ----
    const int idx = bx - 512;
    const int half = idx >> 4, rem = idx & 15;
    gemm_body<0,0,0,0>(smem, smem + 8192, wfb + half * 512, 1024,
                       (half ? wgoT : wloT), 512, nullptr, Wc, nullptr,
                       (rem >> 2) * 128, (rem & 3) * 128, 512, 1024, half * 512);
    return;
  }

  // ---- flash attention: 128-query tile, DMA dbuf, fixed-base softmax ----
  const int lid  = lane & 15;
  const int quad = lane >> 4;
  const int qt = (bx >> 3) & 7;                     // 0..7, 128-query tiles
  const int bh = ((bx & 7) << 3) | (bx >> 6);       // head pinned to XCD=bx&7
  const int b = bh >> 3, h = bh & 7;
  const size_t base = (size_t)b * 1024 * 1536;

  v8bf aq[2][2];
#pragma unroll
  for (int qs = 0; qs < 2; ++qs) {
    const size_t qoff =
        base + (size_t)(qt * 128 + w * 32 + qs * 16 + lid) * 1536 + h * 64 + quad * 8;
    aq[qs][0] = *reinterpret_cast<const v8bf*>(qkv + qoff);
    aq[qs][1] = *reinterpret_cast<const v8bf*>(qkv + qoff + 32);
#pragma unroll
    for (int k = 0; k < 2; ++k)
#pragma unroll
      for (int i = 0; i < 8; ++i)
        aq[qs][k][i] = (__bf16)((float)aq[qs][k][i] * 0.125f);  // exact
  }
  v8bf ones;
#pragma unroll
  for (int i = 0; i < 8; ++i) ones[i] = (__bf16)1.0f;

  v4f o[2][4], lacc[2];
#pragma unroll
  for (int qs = 0; qs < 2; ++qs) {
    lacc[qs] = (v4f){0.f, 0.f, 0.f, 0.f};
#pragma unroll
    for (int nd = 0; nd < 4; ++nd) o[qs][nd] = (v4f){0.f, 0.f, 0.f, 0.f};
  }

  u16* Ps = smem + 16384;          // per-wave 2048 u16 (2 qsets x 16 x 64)
  const int dr = lane >> 3;
  const int dc = lane & 7;
#define STAGE(KT, BI)                                                          \
  {                                                                            \
    _Pragma("unroll") for (int p = 0; p < 2; ++p) {                            \
      const int r = (w + p * 4) * 8 + dr;                                      \
      const int cs = (dc ^ (r & 7)) * 8;                                       \
      load_lds16(qkv + base + (size_t)((KT) * 64 + r) * 1536 + 512 + h * 64 + cs, \
                 smem + (BI) * 4096 + (w + p * 4) * 512);                      \
      load_lds16(vt + ((size_t)bh * 64 + r) * 1024 + (KT) * 64 + cs,           \
                 smem + 8192 + (BI) * 4096 + (w + p * 4) * 512);               \
    }                                                                          \
  }
  STAGE(0, 0);

  for (int kt = 0; kt < 16; ++kt) {
    __syncthreads();
    if (kt < 15) STAGE(kt + 1, (kt + 1) & 1);
    const u16* Ks = smem + (kt & 1) * 4096;
    const u16* Vs = smem + 8192 + (kt & 1) * 4096;

    // K fragments once, reused by both query-sets
    v8bf bk[2][4];
#pragma unroll
    for (int kk = 0; kk < 2; ++kk)
#pragma unroll
      for (int nk = 0; nk < 4; ++nk)
        bk[kk][nk] = *reinterpret_cast<const v8bf*>(
            &Ks[(nk * 16 + lid) * 64 + (((kk * 4 + quad) ^ (lid & 7)) * 8)]);

#pragma unroll
    for (int qs = 0; qs < 2; ++qs) {
      v4f s[4];
#pragma unroll
      for (int nk = 0; nk < 4; ++nk) s[nk] = (v4f){0.f, 0.f, 0.f, 0.f};
      // S^T = K . Q^T : A = K-frag, B = Q-frag (lane mappings identical)
#pragma unroll
      for (int kk = 0; kk < 2; ++kk)
#pragma unroll
        for (int nk = 0; nk < 4; ++nk)
          s[nk] = __builtin_amdgcn_mfma_f32_16x16x32_bf16(
              bk[kk][nk], aq[qs][kk], s[nk], 0, 0, 0);
      // S^T C-layout: row = key = nk*16 + quad*4 + r, col = query = lid.
      // 4 r-values are contiguous keys -> one packed b64 store (truncated
      // bf16; l sums the same truncation).
#pragma unroll
      for (int nk = 0; nk < 4; ++nk) {
        const u32 b0 = __builtin_bit_cast(u32, __expf(s[nk][0]));
        const u32 b1 = __builtin_bit_cast(u32, __expf(s[nk][1]));
        const u32 b2 = __builtin_bit_cast(u32, __expf(s[nk][2]));
        const u32 b3 = __builtin_bit_cast(u32, __expf(s[nk][3]));
        ui2 pk;
        pk.x = (b1 & 0xffff0000u) | (b0 >> 16);
        pk.y = (b3 & 0xffff0000u) | (b2 >> 16);
        const int c8 = (nk * 2 + (quad >> 1)) ^ (lid & 7);
        *reinterpret_cast<ui2*>(
            &Ps[w * 2048 + qs * 1024 + lid * 64 + c8 * 8 + (quad & 1) * 4]) = pk;
      }
    }

    // O^T = V^T P^T ; V fragments once, reused by both query-sets
#pragma unroll
    for (int kk = 0; kk < 2; ++kk) {
      v8bf av[4];
#pragma unroll
      for (int nd = 0; nd < 4; ++nd)
        av[nd] = *reinterpret_cast<const v8bf*>(
            &Vs[(nd * 16 + lid) * 64 + (((kk * 4 + quad) ^ (lid & 7)) * 8)]);
#pragma unroll
      for (int qs = 0; qs < 2; ++qs) {
        const v8bf ap = *reinterpret_cast<const v8bf*>(
            &Ps[w * 2048 + qs * 1024 + lid * 64 + (((kk * 4 + quad) ^ (lid & 7)) * 8)]);
        lacc[qs] = __builtin_amdgcn_mfma_f32_16x16x32_bf16(ones, ap, lacc[qs], 0, 0, 0);
#pragma unroll
        for (int nd = 0; nd < 4; ++nd)
          o[qs][nd] = __builtin_amdgcn_mfma_f32_16x16x32_bf16(
              av[nd], ap, o[qs][nd], 0, 0, 0);
      }
    }
  }
#undef STAGE

#pragma unroll
  for (int qs = 0; qs < 2; ++qs) {
    const float inv = 1.f / lacc[qs][0];
    const int tok = b * 1024 + qt * 128 + w * 32 + qs * 16 + lid;
#pragma unroll
    for (int nd = 0; nd < 4; ++nd) {
      us4 pk;
#pragma unroll
      for (int r = 0; r < 4; ++r) pk[r] = f2bf(o[qs][nd][r] * inv);
      *reinterpret_cast<us4*>(
          &outp[(size_t)tok * 512 + h * 64 + nd * 16 + quad * 4]) = pk;
    }
  }
}

// ---------------------------------------------------------------------------
// Final fused GEMM: out = ReLU([attn_l|attn_g] @ Wc^T + bias_c), fp32 out.
// attn_l lives in qkv_g's V-slots (lda 1536); attn_g is dense (lda 512).
// ---------------------------------------------------------------------------
__global__ void __launch_bounds__(256) gemm_final(
    const u16* __restrict__ Al, const u16* __restrict__ Ag,
    const u16* __restrict__ Bw, const float* __restrict__ biasc,
    float* __restrict__ out)
{
  __shared__ __align__(16) u16 As[64 * 64];
  __shared__ __align__(16) u16 Bs[128 * 64];
  const int tid  = threadIdx.x;
  const int lane = tid & 63;
  const int w    = tid >> 6;
  const int lid  = lane & 15;
  const int quad = lane >> 4;
  const int bm = blockIdx.y * 64;
  const int bn = blockIdx.x * 128;

  v4f acc[4][2];
#pragma unroll
  for (int i = 0; i < 4; ++i)
#pragma unroll
    for (int j = 0; j < 2; ++j)
      acc[i][j] = (v4f){0.f, 0.f, 0.f, 0.f};

  const int dr = lane >> 3;
  const int cs = ((lane ^ dr) & 7) * 8;

  for (int k0 = 0; k0 < 1024; k0 += 64) {
    const int half = k0 >> 9;
    const u16* Asrc = half ? Ag : Al;
    const int  lda  = half ? 512 : 1536;
    const int  kcol = k0 & 511;
#pragma unroll
    for (int p = 0; p < 2; ++p) {
      const int g   = w + p * 4;
      const int row = g * 8 + dr;
      load_lds16(Asrc + (size_t)(bm + row) * lda + kcol + cs, As + g * 512);
    }
#pragma unroll
    for (int p = 0; p < 4; ++p) {
      const int g   = w + p * 4;
      const int row = g * 8 + dr;
      load_lds16(Bw + (size_t)(bn + row) * 1024 + k0 + cs, Bs + g * 512);
    }
    __syncthreads();
#pragma unroll
    for (int kk = 0; kk < 2; ++kk) {
      v8bf af[4], bfr[2];
#pragma unroll
      for (int mi = 0; mi < 4; ++mi)
        af[mi] = *reinterpret_cast<const v8bf*>(
            &As[(mi * 16 + lid) * 64 + (((kk * 4 + quad) ^ (lid & 7)) * 8)]);
#pragma unroll
      for (int ni = 0; ni < 2; ++ni)
        bfr[ni] = *reinterpret_cast<const v8bf*>(
            &Bs[(w * 32 + ni * 16 + lid) * 64 + (((kk * 4 + quad) ^ (lid & 7)) * 8)]);
#pragma unroll
      for (int mi = 0; mi < 4; ++mi)
#pragma unroll
        for (int ni = 0; ni < 2; ++ni)
          acc[mi][ni] = __builtin_amdgcn_mfma_f32_16x16x32_bf16(
              af[mi], bfr[ni], acc[mi][ni], 0, 0, 0);
    }
    __syncthreads();
  }

#pragma unroll
  for (int mi = 0; mi < 4; ++mi) {
#pragma unroll
    for (int ni = 0; ni < 2; ++ni) {
      const int n = bn + w * 32 + ni * 16 + lid;
      const float bv = biasc[n];
#pragma unroll
      for (int r = 0; r < 4; ++r) {
        const int m = bm + mi * 16 + quad * 4 + r;
        out[(size_t)m * 512 + n] = fmaxf(acc[mi][ni][r] + bv, 0.f);
      }
    }
  }
}

// ---------------------------------------------------------------------------
// Workspace (u16 elems), total 36701184 = 73.4 MB:
//   0        xb (dead after qkv_dual -> attn_g) | 4194304 wli | 4980736 wgi
//   5767168  wfb | 6291456 qkv_l | 18874368 qkv_g (V-thirds = attn_l)
//   31457280 vt | 35651584 Wc | 36175872 bias_c | 36176896 wloT | 36439040 wgoT
// ---------------------------------------------------------------------------
extern "C" void kernel_launch(void* const* d_in, const int* in_sizes, int n_in,
                              void* d_out, int out_size, void* d_ws, size_t ws_size,
                              hipStream_t stream) {
  (void)in_sizes; (void)n_in; (void)out_size; (void)ws_size;
  const float* x   = (const float*)d_in[0];
  const float* Wli = (const float*)d_in[1];
  const float* bli = (const float*)d_in[2];
  const float* Wlo = (const float*)d_in[3];
  const float* blo = (const float*)d_in[4];
  const float* Wgi = (const float*)d_in[5];
  const float* bgi = (const float*)d_in[6];
  const float* Wgo = (const float*)d_in[7];
  const float* bgo = (const float*)d_in[8];
  const float* Wf  = (const float*)d_in[9];
  const float* bff = (const float*)d_in[10];
  float* out = (float*)d_out;

  u16* W      = (u16*)d_ws;
  u16* xb     = W + 0;
  u16* wli    = W + 4194304;
  u16* wgi    = W + 4980736;
  u16* wfb    = W + 5767168;
  u16* qkv_l  = W + 6291456;
  u16* qkv_g  = W + 18874368;
  u16* vt     = W + 31457280;
  u16* Wc     = W + 35651584;
  float* bias_c = (float*)(W + 36175872);
  u16* wloT   = W + 36176896;
  u16* wgoT   = W + 36439040;
  u16* attn_g = W + 0;                  // over dead xb
  u16* attn_l = qkv_g + 1024;           // dead V-thirds of qkv_g, lda 1536

  cvt_all<<<6656, 256, 0, stream>>>(x, Wli, Wlo, Wgi, Wgo, Wf, W, wloT, wgoT);
  qkv_dual<<<dim3(24, 64), 256, 0, stream>>>(xb, wli, bli, qkv_l, wgi, bgi, qkv_g, vt);
  mega<<<1576, 256, 0, stream>>>(qkv_g, vt, attn_g, wfb, wloT, wgoT, Wc,
                                 blo, bgo, bff, bias_c, qkv_l, attn_l);
  gemm_final<<<dim3(4, 128), 256, 0, stream>>>(attn_l, attn_g, Wc, bias_c, out);
}